// Round 11
// baseline (176.486 us; speedup 1.0000x reference)
//
#include <hip/hip_runtime.h>

// Problem constants (fp32 RQ-VAE nearest-codebook step)
#define Bn 8192
#define Kn 8192
#define Dn 512
#define WINDOW 0.25f   // refine window: covers f16-noise + 8-bit mantissa packing

typedef _Float16 half8 __attribute__((ext_vector_type(8)));
typedef float floatx4 __attribute__((ext_vector_type(4)));
typedef unsigned long long u64;

// Order-preserving map float -> u32 (monotone under unsigned compare, finite inputs)
__device__ __forceinline__ unsigned int fkey(float f) {
    unsigned int u = __float_as_uint(f);
    return (u & 0x80000000u) ? ~u : (u | 0x80000000u);
}

// async global->LDS, 16B per lane (global_load_lds_dwordx4)
__device__ __forceinline__ void gld16(const _Float16* g, _Float16* l) {
    __builtin_amdgcn_global_load_lds(
        (const __attribute__((address_space(1))) unsigned int*)g,
        (__attribute__((address_space(3))) unsigned int*)l, 16, 0, 0);
}

// ---------------- kernel: e_sq (fallback path only) ----------------
__global__ __launch_bounds__(256) void esq_kernel(const float* __restrict__ E,
                                                  float* __restrict__ esq) {
    int wave = threadIdx.x >> 6;
    int lane = threadIdx.x & 63;
    int k = blockIdx.x * 4 + wave;
    const float4* row = (const float4*)(E + (size_t)k * Dn);
    float4 v0 = row[lane];
    float4 v1 = row[64 + lane];
    float s = v0.x*v0.x + v0.y*v0.y + v0.z*v0.z + v0.w*v0.w
            + v1.x*v1.x + v1.y*v1.y + v1.z*v1.z + v1.w*v1.w;
    #pragma unroll
    for (int off = 32; off > 0; off >>= 1) s += __shfl_down(s, off, 64);
    if (lane == 0) esq[k] = s;
}

// ---------------- kernel: fp32 -> f16 (hi), PACKED layout, + fused e_sq ------
// G[panel][chunk][slot]*8 halves, panel = 128 rows, chunk = 32 k-halves,
//   slot(row128, kq) = (row128>>6)*256 + ((row128>>4)&3)*64 + kq*16 + (row128&15)
// blocks [0,1024) pack X, [1024,2048) pack E (E blocks also atomicAdd e_sq
// partials; esq must be zeroed before launch).
// r11 CHANGE (tail hypothesis): the direct packed-slot stores were 16B
// SCATTERED writes (runs ~256B with jumps) -> suspected 2-4x write-coalescing
// loss making convert a large part of the stable ~78us non-argmin tail.
// FIX: scatter the block's 8KB output unit into LDS (cheap), barrier, then
// flush LINEARLY: each thread 2x16B contiguous -> wave = 2KB runs, fully
// coalesced. Slot bijection unchanged (rows 0..127 x kq 0..3 <-> slots 0..511).
__global__ __launch_bounds__(256) void convert_hi(
    const float* __restrict__ X, const float* __restrict__ E,
    _Float16* __restrict__ Xh, _Float16* __restrict__ Eh,
    float* __restrict__ esq)
{
    __shared__ __align__(16) _Float16 sOut[4096];   // 8KB staging of one unit

    const bool isE = blockIdx.x >= 1024;
    const int pc = blockIdx.x & 1023;
    const int panel = pc >> 4;              // 64 panels of 128 rows
    const int chunk = pc & 15;              // 16 chunks of 32 halves
    const float* src = isE ? E : X;
    _Float16* dst = isE ? Eh : Xh;
    const int t = threadIdx.x;
    const int row = t >> 1;                 // [0,128)
    const int kh  = (t & 1) * 16;
    const float* p = &src[(size_t)(panel * 128 + row) * Dn + chunk * 32 + kh];
    float4 v[4];
    v[0] = *(const float4*)(p + 0);
    v[1] = *(const float4*)(p + 4);
    v[2] = *(const float4*)(p + 8);
    v[3] = *(const float4*)(p + 12);
    const int slotbase = ((row >> 6) << 8) + (((row >> 4) & 3) << 6) + (row & 15);
    #pragma unroll
    for (int j = 0; j < 2; ++j) {
        half8 h;
        #pragma unroll
        for (int q = 0; q < 2; ++q) {
            const float4 w = v[j * 2 + q];
            h[q*4+0]=(_Float16)w.x; h[q*4+1]=(_Float16)w.y;
            h[q*4+2]=(_Float16)w.z; h[q*4+3]=(_Float16)w.w;
        }
        const int kq = (t & 1) * 2 + j;
        *(half8*)&sOut[(slotbase + kq * 16) * 8] = h;   // LDS scatter
    }
    if (isE) {
        float s = 0.f;
        #pragma unroll
        for (int i = 0; i < 4; ++i)
            s += v[i].x*v[i].x + v[i].y*v[i].y + v[i].z*v[i].z + v[i].w*v[i].w;
        s += __shfl_xor(s, 1);              // pair (kh=0, kh=16) -> 32-col partial
        if ((t & 1) == 0) atomicAdd(&esq[panel * 128 + row], s);
    }
    __syncthreads();
    // linear flush: thread t writes halves [t*16, t*16+16) -> fully coalesced
    _Float16* ub = dst + (size_t)(panel * 16 + chunk) * 4096;
    *(half8*)&ub[t * 16]     = *(const half8*)&sOut[t * 16];
    *(half8*)&ub[t * 16 + 8] = *(const half8*)&sOut[t * 16 + 8];
}

// ---------------- kernel: hi-only MFMA, 128x256, tri-buffer counted vmcnt ----
// d~(b,k) = e_sq[k] - 2*(xh.eh). Wave tile 64x64 (acc 4x4 = 64 VGPR), 8 waves
// (wm 2 x wn 4), __launch_bounds__(512,4) -> 128 unified regs -> 4 waves/SIMD
// (r8 VERIFIED: Occupancy 21->40%, 91us). r10: tri-buffer + counted vmcnt(3)
// was NULL vs r8's dbuf+vmcnt(0) (92.1 vs 91.1us, within noise) -> exposed
// load latency exonerated; residual is the post-barrier LDS read burst (128
// b128/CU/interval ~1060cyc) serializing ahead of the MFMA tail (~620cyc =
// 36% MfmaUtil, matches measured 32.5%). Reg wall (acc64+temps32+addr ~128)
// blocks operand-direct variants; kept as-is this round (tail test instead).
__global__ __launch_bounds__(512, 4) void argmin_hi(
    const _Float16* __restrict__ Xh, const _Float16* __restrict__ Eh,
    const float* __restrict__ esq, float* __restrict__ bestf)
{
    __shared__ __align__(16) _Float16 sA[3][4096];      // [buf][128r x 32k] 24KB
    __shared__ __align__(16) _Float16 sB[3][2][4096];   // [buf][panel][...] 48KB

    const int tid  = threadIdx.x;
    const int bid  = blockIdx.x;
    const int bx   = bid & 31;           // 32 col-blocks of 256 (bx%8 -> XCD set)
    const int by   = bid >> 5;           // 64 row-blocks of 128
    const int lane = tid & 63, wave = tid >> 6;
    const int wm   = wave >> 2;          // 0..1: 64-row half
    const int wn   = wave & 3;           // 0..3: 64-col quarter
    const int colg = lane & 15, quad = lane >> 4;
    const int la8  = lane * 8;

    const _Float16* gA = Xh + (size_t)by * 65536 + tid * 8;
    const _Float16* gB = Eh + (size_t)(2 * bx) * 65536 + tid * 8;

    // stage chunk t into LDS buffer b (A: 1 gld16, B: 2 gld16 @ 512 thr)
    auto stage = [&](int t, int b) {
        gld16(gA + t * 4096,         &sA[b][tid * 8]);
        gld16(gB + t * 4096,         &sB[b][0][tid * 8]);
        gld16(gB + 65536 + t * 4096, &sB[b][1][tid * 8]);
    };

    floatx4 acc[4][4];
    #pragma unroll
    for (int i = 0; i < 4; ++i)
        #pragma unroll
        for (int j = 0; j < 4; ++j) acc[i][j] = {0.f, 0.f, 0.f, 0.f};

    // prologue: chunks 0,1 in flight (6 loads/thread)
    stage(0, 0);
    stage(1, 1);

    #pragma unroll
    for (int t = 0; t < 16; ++t) {
        const int b = t % 3;
        // publish chunk t: drain its 3 loads, keep chunk t+1's 3 in flight
        if (t < 15) asm volatile("s_waitcnt vmcnt(3)" ::: "memory");
        else        asm volatile("s_waitcnt vmcnt(0)" ::: "memory");
        __builtin_amdgcn_s_barrier();
        // stage chunk t+2 into buf (t+2)%3 = buffer read in iter t-1; the
        // barrier above retired all its readers -> race-free
        if (t + 2 < 16) stage(t + 2, (t + 2) % 3);

        const _Float16* A0 = &sA[b][wm * 2048 + la8];
        const _Float16* B0 = &sB[b][wn >> 1][(wn & 1) * 2048 + la8];
        half8 a[4], bb[4];
        #pragma unroll
        for (int ni = 0; ni < 4; ++ni) bb[ni] = *(const half8*)&B0[ni * 512];
        #pragma unroll
        for (int mi = 0; mi < 4; ++mi) a[mi] = *(const half8*)&A0[mi * 512];

        __builtin_amdgcn_s_setprio(1);
        #pragma unroll
        for (int mi = 0; mi < 4; ++mi)
            #pragma unroll
            for (int ni = 0; ni < 4; ++ni)
                acc[mi][ni] = __builtin_amdgcn_mfma_f32_16x16x32_f16(
                    a[mi], bb[ni], acc[mi][ni], 0, 0, 0);
        __builtin_amdgcn_s_setprio(0);
    }

    // ---- epilogue: per-(mi,r) top-2 over the wave's 64 cols, then cross-wn
    // merge in LDS -> top-2 per 256-col block (encoding identical to r3/r8).
    // sm lives in sA[1] (4KB): t=15 read buf 0; sA[1] last read at t=13 and
    // all waves passed the t=15 barrier since -> disjoint/retired.
    float2* sm = (float2*)&sA[1][0];
    const int n0 = bx * 256 + wn * 64;
    float eqv[4];
    #pragma unroll
    for (int ni = 0; ni < 4; ++ni) eqv[ni] = esq[n0 + ni * 16 + colg];
    const unsigned ob_base = ((unsigned)colg << 4) | ((unsigned)wn << 2);

    #pragma unroll
    for (int mi = 0; mi < 4; ++mi)
        #pragma unroll
        for (int r = 0; r < 4; ++r) {
            float w1 = INFINITY, w2 = INFINITY;
            #pragma unroll
            for (int ni = 0; ni < 4; ++ni) {
                const float dv = eqv[ni] - 2.0f * acc[mi][ni][r];
                const float key = __uint_as_float(
                    (__float_as_uint(dv) & 0xFFFFFF00u) | (ob_base | (unsigned)ni));
                w2 = fminf(w2, fmaxf(w1, key));
                w1 = fminf(w1, key);
            }
            #pragma unroll
            for (int off = 1; off < 16; off <<= 1) {
                const float p1 = __shfl_xor(w1, off);
                const float p2 = __shfl_xor(w2, off);
                w2 = fminf(fmaxf(w1, p1), fminf(w2, p2));
                w1 = fminf(w1, p1);
            }
            if (colg == 0) {
                const int row128 = wm * 64 + mi * 16 + quad * 4 + r;
                float2 st; st.x = w1; st.y = w2;
                sm[row128 * 4 + wn] = st;
            }
        }
    __syncthreads();
    if (tid < 128) {
        float m1 = INFINITY, m2 = INFINITY;
        #pragma unroll
        for (int w = 0; w < 4; ++w) {
            const float2 p = sm[tid * 4 + w];
            m2 = fminf(fmaxf(m1, p.x), fminf(m2, p.y));
            m1 = fminf(m1, p.x);
        }
        float2 st; st.x = m1; st.y = m2;
        *(float2*)&bestf[(size_t)(by * 128 + tid) * 64 + bx * 2] = st;
    }
}

// ---------------- kernel: exact refine, ONE WAVE PER ROW ---------------------
// 64 lanes read the row's 64 stored keys (top-2 per 256-col block), wave-min
// -> threshold -> ballot survivors -> exact fp32 distance per survivor ->
// best index (u64 key: ties to lowest index) -> write index + residual.
__global__ __launch_bounds__(256) void refine_kernel(
    const float* __restrict__ X, const float* __restrict__ E,
    const float* __restrict__ bestf, float* __restrict__ out)
{
    const int lane = threadIdx.x & 63, wave = threadIdx.x >> 6;
    const int b = blockIdx.x * 4 + wave;

    const float val = bestf[(size_t)b * 64 + lane];
    // decode this slot's candidate column: slot = cb*2 + j, cb = 256-col block
    const unsigned bits = __float_as_uint(val);
    const int cb = lane >> 1;
    const int colg = (bits >> 4) & 15, wn = (bits >> 2) & 3, ni = bits & 3;
    const int col = cb * 256 + wn * 64 + ni * 16 + colg;

    float mn = val;
    #pragma unroll
    for (int off = 1; off < 64; off <<= 1) mn = fminf(mn, __shfl_xor(mn, off));

    const float4* xr = (const float4*)(X + (size_t)b * Dn);
    const float4 x0 = xr[lane * 2], x1 = xr[lane * 2 + 1];

    u64 bestk = ~0ull;
    u64 mask = __ballot(val <= mn + WINDOW);
    while (mask) {
        const int s = __builtin_ctzll(mask);
        mask &= mask - 1;
        const int c = __shfl(col, s);
        const float4* er = (const float4*)(E + (size_t)c * Dn);
        const float4 e0 = er[lane * 2], e1 = er[lane * 2 + 1];
        float p = e0.x*(e0.x - 2.f*x0.x) + e0.y*(e0.y - 2.f*x0.y)
                + e0.z*(e0.z - 2.f*x0.z) + e0.w*(e0.w - 2.f*x0.w)
                + e1.x*(e1.x - 2.f*x1.x) + e1.y*(e1.y - 2.f*x1.y)
                + e1.z*(e1.z - 2.f*x1.z) + e1.w*(e1.w - 2.f*x1.w);
        #pragma unroll
        for (int off = 1; off < 64; off <<= 1) p += __shfl_xor(p, off);
        const u64 k = ((u64)fkey(p) << 32) | (u64)(unsigned int)c;
        if (k < bestk) bestk = k;
    }

    const int idx = (int)(unsigned int)(bestk & 0xFFFFFFFFull);
    if (lane == 0) out[b] = (float)idx;
    const float4* er = (const float4*)(E + (size_t)idx * Dn);
    const float4 e0 = er[lane * 2], e1 = er[lane * 2 + 1];
    float4 r0, r1;
    r0.x = x0.x - e0.x; r0.y = x0.y - e0.y; r0.z = x0.z - e0.z; r0.w = x0.w - e0.w;
    r1.x = x1.x - e1.x; r1.y = x1.y - e1.y; r1.z = x1.z - e1.z; r1.w = x1.w - e1.w;
    float4* o = (float4*)(out + Bn + (size_t)b * Dn);
    o[lane * 2] = r0; o[lane * 2 + 1] = r1;
}

// ---------------- fallback (round-1 fp32 path, used only if ws too small) ----
#define KSPLIT 16
#define LDSW 132
__global__ __launch_bounds__(256, 2) void argmin_fp32(
    const float* __restrict__ X, const float* __restrict__ E,
    const float* __restrict__ esq, u64* __restrict__ best)
{
    __shared__ __align__(16) float Xs[16][LDSW];
    __shared__ __align__(16) float Es[16][LDSW];
    __shared__ u64 red[128][16];
    const int tid = threadIdx.x;
    const int tx = tid & 15, ty = tid >> 4;
    const int rowTile = blockIdx.x / KSPLIT;
    const int split   = blockIdx.x % KSPLIT;
    const int m0 = rowTile * 128;
    const int kbase = split * (Kn / KSPLIT);
    float bestv[8]; int besti[8];
    #pragma unroll
    for (int i = 0; i < 8; ++i) { bestv[i] = INFINITY; besti[i] = 0; }
    const int ldRow = tid >> 2, ldD = (tid & 3) * 4;
    for (int kt = 0; kt < (Kn / KSPLIT) / 128; ++kt) {
        const int k0 = kbase + kt * 128;
        float acc[8][8] = {};
        for (int dc = 0; dc < Dn / 16; ++dc) {
            const int d0 = dc * 16;
            float4 xa = *(const float4*)&X[(size_t)(m0 + ldRow)      * Dn + d0 + ldD];
            float4 xb = *(const float4*)&X[(size_t)(m0 + 64 + ldRow) * Dn + d0 + ldD];
            float4 ea = *(const float4*)&E[(size_t)(k0 + ldRow)      * Dn + d0 + ldD];
            float4 eb = *(const float4*)&E[(size_t)(k0 + 64 + ldRow) * Dn + d0 + ldD];
            __syncthreads();
            Xs[ldD+0][ldRow] = xa.x; Xs[ldD+1][ldRow] = xa.y;
            Xs[ldD+2][ldRow] = xa.z; Xs[ldD+3][ldRow] = xa.w;
            Xs[ldD+0][64+ldRow] = xb.x; Xs[ldD+1][64+ldRow] = xb.y;
            Xs[ldD+2][64+ldRow] = xb.z; Xs[ldD+3][64+ldRow] = xb.w;
            Es[ldD+0][ldRow] = ea.x; Es[ldD+1][ldRow] = ea.y;
            Es[ldD+2][ldRow] = ea.z; Es[ldD+3][ldRow] = ea.w;
            Es[ldD+0][64+ldRow] = eb.x; Es[ldD+1][64+ldRow] = eb.y;
            Es[ldD+2][64+ldRow] = eb.z; Es[ldD+3][64+ldRow] = eb.w;
            __syncthreads();
            #pragma unroll
            for (int d = 0; d < 16; ++d) {
                float a8[8], b8[8];
                *(float4*)&a8[0] = *(const float4*)&Xs[d][4*ty];
                *(float4*)&a8[4] = *(const float4*)&Xs[d][64 + 4*ty];
                *(float4*)&b8[0] = *(const float4*)&Es[d][4*tx];
                *(float4*)&b8[4] = *(const float4*)&Es[d][64 + 4*tx];
                #pragma unroll
                for (int i = 0; i < 8; ++i)
                    #pragma unroll
                    for (int j = 0; j < 8; ++j) acc[i][j] += a8[i] * b8[j];
            }
        }
        #pragma unroll
        for (int j = 0; j < 8; ++j) {
            const int c = k0 + ((j < 4) ? (4*tx + j) : (64 + 4*tx + (j - 4)));
            const float eq = esq[c];
            #pragma unroll
            for (int i = 0; i < 8; ++i) {
                float dval = eq - 2.0f * acc[i][j];
                if (dval < bestv[i]) { bestv[i] = dval; besti[i] = c; }
            }
        }
    }
    #pragma unroll
    for (int i = 0; i < 8; ++i) {
        int rloc = (i < 4) ? (4*ty + i) : (64 + 4*ty + (i - 4));
        red[rloc][tx] = ((u64)fkey(bestv[i]) << 32) | (u64)(unsigned int)besti[i];
    }
    __syncthreads();
    if (tid < 128) {
        u64 m = red[tid][0];
        #pragma unroll
        for (int t = 1; t < 16; ++t) { u64 v = red[tid][t]; if (v < m) m = v; }
        best[(size_t)(m0 + tid) * KSPLIT + split] = m;
    }
}

__global__ __launch_bounds__(256) void finalize_kernel(
    const float* __restrict__ X, const float* __restrict__ E,
    const u64* __restrict__ best, float* __restrict__ out, int nsplits)
{
    __shared__ int sidx[2];
    const int half = threadIdx.x >> 7;
    const int t    = threadIdx.x & 127;
    const int b    = blockIdx.x * 2 + half;
    if (t < 64) {
        u64 v = (t < nsplits) ? best[(size_t)b * nsplits + t] : ~0ull;
        #pragma unroll
        for (int off = 1; off < 64; off <<= 1) {
            u64 o = __shfl_xor(v, off);
            if (o < v) v = o;
        }
        if (t == 0) {
            int idx = (int)(unsigned int)(v & 0xFFFFFFFFull);
            sidx[half] = idx;
            out[b] = (float)idx;
        }
    }
    __syncthreads();
    const int idx = sidx[half];
    float4 x = ((const float4*)(X + (size_t)b * Dn))[t];
    float4 e = ((const float4*)(E + (size_t)idx * Dn))[t];
    float4 r; r.x = x.x - e.x; r.y = x.y - e.y; r.z = x.z - e.z; r.w = x.w - e.w;
    ((float4*)(out + Bn + (size_t)b * Dn))[t] = r;
}

extern "C" void kernel_launch(void* const* d_in, const int* in_sizes, int n_in,
                              void* d_out, int out_size, void* d_ws, size_t ws_size,
                              hipStream_t stream) {
    const float* X = (const float*)d_in[0];   // previous_residual [B, D]
    const float* E = (const float*)d_in[1];   // codebook_embeddings [K, D]
    float* out = (float*)d_out;               // [B] idx-as-float ++ [B*D] residual

    // fast-path ws: esq 32KB | Xh 8MB | Eh 8MB | bestf 2MB  (~18.3 MB)
    const size_t HB = (size_t)Bn * Dn * sizeof(_Float16);        // 8 MB
    const size_t BESTB = (size_t)Bn * 64 * sizeof(float);        // 2 MB
    const size_t NEED = 32768 + 2 * HB + BESTB;

    float* esq = (float*)d_ws;

    if (ws_size >= NEED) {
        _Float16* Xh = (_Float16*)((char*)d_ws + 32768);
        _Float16* Eh = (_Float16*)((char*)d_ws + 32768 + HB);
        float* bestf = (float*)((char*)d_ws + 32768 + 2 * HB);
        hipMemsetAsync((void*)esq, 0, Kn * sizeof(float), stream);
        convert_hi<<<2048, 256, 0, stream>>>(X, E, Xh, Eh, esq);
        argmin_hi<<<2048, 512, 0, stream>>>(Xh, Eh, esq, bestf);
        refine_kernel<<<Bn / 4, 256, 0, stream>>>(X, E, bestf, out);
    } else {
        u64* best = (u64*)((char*)d_ws + 32768);
        esq_kernel<<<Kn / 4, 256, 0, stream>>>(E, esq);
        argmin_fp32<<<(Bn / 128) * KSPLIT, 256, 0, stream>>>(X, E, esq, best);
        finalize_kernel<<<Bn / 2, 256, 0, stream>>>(X, E, best, out, KSPLIT);
    }
}

// Round 12
// 169.350 us; speedup vs baseline: 1.0421x; 1.0421x over previous
//
#include <hip/hip_runtime.h>

// Problem constants (fp32 RQ-VAE nearest-codebook step)
#define Bn 8192
#define Kn 8192
#define Dn 512
#define WINDOW 0.25f   // refine window: covers f16-noise + 8-bit mantissa packing

typedef _Float16 half8 __attribute__((ext_vector_type(8)));
typedef float floatx4 __attribute__((ext_vector_type(4)));
typedef unsigned long long u64;

// Order-preserving map float -> u32 (monotone under unsigned compare, finite inputs)
__device__ __forceinline__ unsigned int fkey(float f) {
    unsigned int u = __float_as_uint(f);
    return (u & 0x80000000u) ? ~u : (u | 0x80000000u);
}

// async global->LDS, 16B per lane (global_load_lds_dwordx4)
__device__ __forceinline__ void gld16(const _Float16* g, _Float16* l) {
    __builtin_amdgcn_global_load_lds(
        (const __attribute__((address_space(1))) unsigned int*)g,
        (__attribute__((address_space(3))) unsigned int*)l, 16, 0, 0);
}

// ---------------- kernel: e_sq (fallback path only) ----------------
__global__ __launch_bounds__(256) void esq_kernel(const float* __restrict__ E,
                                                  float* __restrict__ esq) {
    int wave = threadIdx.x >> 6;
    int lane = threadIdx.x & 63;
    int k = blockIdx.x * 4 + wave;
    const float4* row = (const float4*)(E + (size_t)k * Dn);
    float4 v0 = row[lane];
    float4 v1 = row[64 + lane];
    float s = v0.x*v0.x + v0.y*v0.y + v0.z*v0.z + v0.w*v0.w
            + v1.x*v1.x + v1.y*v1.y + v1.z*v1.z + v1.w*v1.w;
    #pragma unroll
    for (int off = 32; off > 0; off >>= 1) s += __shfl_down(s, off, 64);
    if (lane == 0) esq[k] = s;
}

// ---------------- kernel: fp32 -> f16 (hi), PACKED layout, + fused e_sq ------
// G[panel][chunk][slot]*8 halves, panel = 128 rows, chunk = 32 k-halves,
//   slot(row128, kq) = (row128>>6)*256 + ((row128>>4)&3)*64 + kq*16 + (row128&15)
// blocks [0,1024) pack X, [1024,2048) pack E (E blocks also atomicAdd e_sq
// partials; esq must be zeroed before launch).
// r11 LESSON: direct 16B stores all land inside one contiguous 8KB unit per
// block -> every 64B line fully covered -> NO coalescing loss. The r11 LDS
// roundtrip "fix" regressed 5us (pure added traffic+barrier). Reverted.
__global__ __launch_bounds__(256) void convert_hi(
    const float* __restrict__ X, const float* __restrict__ E,
    _Float16* __restrict__ Xh, _Float16* __restrict__ Eh,
    float* __restrict__ esq)
{
    const bool isE = blockIdx.x >= 1024;
    const int pc = blockIdx.x & 1023;
    const int panel = pc >> 4;              // 64 panels of 128 rows
    const int chunk = pc & 15;              // 16 chunks of 32 halves
    const float* src = isE ? E : X;
    _Float16* dst = isE ? Eh : Xh;
    const int t = threadIdx.x;
    const int row = t >> 1;                 // [0,128)
    const int kh  = (t & 1) * 16;
    const float* p = &src[(size_t)(panel * 128 + row) * Dn + chunk * 32 + kh];
    float4 v[4];
    v[0] = *(const float4*)(p + 0);
    v[1] = *(const float4*)(p + 4);
    v[2] = *(const float4*)(p + 8);
    v[3] = *(const float4*)(p + 12);
    const int slotbase = ((row >> 6) << 8) + (((row >> 4) & 3) << 6) + (row & 15);
    #pragma unroll
    for (int j = 0; j < 2; ++j) {
        half8 h;
        #pragma unroll
        for (int q = 0; q < 2; ++q) {
            const float4 w = v[j * 2 + q];
            h[q*4+0]=(_Float16)w.x; h[q*4+1]=(_Float16)w.y;
            h[q*4+2]=(_Float16)w.z; h[q*4+3]=(_Float16)w.w;
        }
        const int kq = (t & 1) * 2 + j;
        const size_t off = ((size_t)(panel * 16 + chunk) * 512
                            + slotbase + kq * 16) * 8;
        *(half8*)&dst[off] = h;
    }
    if (isE) {
        float s = 0.f;
        #pragma unroll
        for (int i = 0; i < 4; ++i)
            s += v[i].x*v[i].x + v[i].y*v[i].y + v[i].z*v[i].z + v[i].w*v[i].w;
        s += __shfl_xor(s, 1);              // pair (kh=0, kh=16) -> 32-col partial
        if ((t & 1) == 0) atomicAdd(&esq[panel * 128 + row], s);
    }
}

// ---------------- kernel: hi-only MFMA, 128x256, tri-buffer counted vmcnt ----
// d~(b,k) = e_sq[k] - 2*(xh.eh). Wave tile 64x64 (acc 4x4 = 64 VGPR), 8 waves
// (wm 2 x wn 4), __launch_bounds__(512,4) -> 128 unified regs -> 4 waves/SIMD
// (r8 VERIFIED: Occupancy 21->40%, 91us). r10: tri-buffer + counted vmcnt(3)
// = NULL vs dbuf+vmcnt(0) (92.1 vs 91.1, noise) -> load latency exonerated.
// r11 model: interval ~1725cyc vs 128 ds_read_b128 x ~12cyc issue = ~1536cyc
// -> argmin at ~85-90% of its LDS-issue floor. 8 reads/wave/chunk is
// width-minimal; all escapes (bigger tile, reg-prefetch, B-in-regs) break the
// 128-reg/4-waves-SIMD cap (r6/r8 measured) and fewer barriers needs 96KB ->
// 1 block/CU. STRUCTURALLY AT OPTIMUM (~92us, <=10% headroom left).
__global__ __launch_bounds__(512, 4) void argmin_hi(
    const _Float16* __restrict__ Xh, const _Float16* __restrict__ Eh,
    const float* __restrict__ esq, float* __restrict__ bestf)
{
    __shared__ __align__(16) _Float16 sA[3][4096];      // [buf][128r x 32k] 24KB
    __shared__ __align__(16) _Float16 sB[3][2][4096];   // [buf][panel][...] 48KB

    const int tid  = threadIdx.x;
    const int bid  = blockIdx.x;
    const int bx   = bid & 31;           // 32 col-blocks of 256 (bx%8 -> XCD set)
    const int by   = bid >> 5;           // 64 row-blocks of 128
    const int lane = tid & 63, wave = tid >> 6;
    const int wm   = wave >> 2;          // 0..1: 64-row half
    const int wn   = wave & 3;           // 0..3: 64-col quarter
    const int colg = lane & 15, quad = lane >> 4;
    const int la8  = lane * 8;

    const _Float16* gA = Xh + (size_t)by * 65536 + tid * 8;
    const _Float16* gB = Eh + (size_t)(2 * bx) * 65536 + tid * 8;

    // stage chunk t into LDS buffer b (A: 1 gld16, B: 2 gld16 @ 512 thr)
    auto stage = [&](int t, int b) {
        gld16(gA + t * 4096,         &sA[b][tid * 8]);
        gld16(gB + t * 4096,         &sB[b][0][tid * 8]);
        gld16(gB + 65536 + t * 4096, &sB[b][1][tid * 8]);
    };

    floatx4 acc[4][4];
    #pragma unroll
    for (int i = 0; i < 4; ++i)
        #pragma unroll
        for (int j = 0; j < 4; ++j) acc[i][j] = {0.f, 0.f, 0.f, 0.f};

    // prologue: chunks 0,1 in flight (6 loads/thread)
    stage(0, 0);
    stage(1, 1);

    #pragma unroll
    for (int t = 0; t < 16; ++t) {
        const int b = t % 3;
        // publish chunk t: drain its 3 loads, keep chunk t+1's 3 in flight
        if (t < 15) asm volatile("s_waitcnt vmcnt(3)" ::: "memory");
        else        asm volatile("s_waitcnt vmcnt(0)" ::: "memory");
        __builtin_amdgcn_s_barrier();
        // stage chunk t+2 into buf (t+2)%3 = buffer read in iter t-1; the
        // barrier above retired all its readers -> race-free
        if (t + 2 < 16) stage(t + 2, (t + 2) % 3);

        const _Float16* A0 = &sA[b][wm * 2048 + la8];
        const _Float16* B0 = &sB[b][wn >> 1][(wn & 1) * 2048 + la8];
        half8 a[4], bb[4];
        #pragma unroll
        for (int ni = 0; ni < 4; ++ni) bb[ni] = *(const half8*)&B0[ni * 512];
        #pragma unroll
        for (int mi = 0; mi < 4; ++mi) a[mi] = *(const half8*)&A0[mi * 512];

        __builtin_amdgcn_s_setprio(1);
        #pragma unroll
        for (int mi = 0; mi < 4; ++mi)
            #pragma unroll
            for (int ni = 0; ni < 4; ++ni)
                acc[mi][ni] = __builtin_amdgcn_mfma_f32_16x16x32_f16(
                    a[mi], bb[ni], acc[mi][ni], 0, 0, 0);
        __builtin_amdgcn_s_setprio(0);
    }

    // ---- epilogue: per-(mi,r) top-2 over the wave's 64 cols, then cross-wn
    // merge in LDS -> top-2 per 256-col block (encoding identical to r3/r8).
    // sm lives in sA[1] (4KB): t=15 read buf 0 -> disjoint/retired.
    float2* sm = (float2*)&sA[1][0];
    const int n0 = bx * 256 + wn * 64;
    float eqv[4];
    #pragma unroll
    for (int ni = 0; ni < 4; ++ni) eqv[ni] = esq[n0 + ni * 16 + colg];
    const unsigned ob_base = ((unsigned)colg << 4) | ((unsigned)wn << 2);

    #pragma unroll
    for (int mi = 0; mi < 4; ++mi)
        #pragma unroll
        for (int r = 0; r < 4; ++r) {
            float w1 = INFINITY, w2 = INFINITY;
            #pragma unroll
            for (int ni = 0; ni < 4; ++ni) {
                const float dv = eqv[ni] - 2.0f * acc[mi][ni][r];
                const float key = __uint_as_float(
                    (__float_as_uint(dv) & 0xFFFFFF00u) | (ob_base | (unsigned)ni));
                w2 = fminf(w2, fmaxf(w1, key));
                w1 = fminf(w1, key);
            }
            #pragma unroll
            for (int off = 1; off < 16; off <<= 1) {
                const float p1 = __shfl_xor(w1, off);
                const float p2 = __shfl_xor(w2, off);
                w2 = fminf(fmaxf(w1, p1), fminf(w2, p2));
                w1 = fminf(w1, p1);
            }
            if (colg == 0) {
                const int row128 = wm * 64 + mi * 16 + quad * 4 + r;
                float2 st; st.x = w1; st.y = w2;
                sm[row128 * 4 + wn] = st;
            }
        }
    __syncthreads();
    if (tid < 128) {
        float m1 = INFINITY, m2 = INFINITY;
        #pragma unroll
        for (int w = 0; w < 4; ++w) {
            const float2 p = sm[tid * 4 + w];
            m2 = fminf(fmaxf(m1, p.x), fminf(m2, p.y));
            m1 = fminf(m1, p.x);
        }
        float2 st; st.x = m1; st.y = m2;
        *(float2*)&bestf[(size_t)(by * 128 + tid) * 64 + bx * 2] = st;
    }
}

// ---------------- kernel: exact refine, ONE WAVE PER ROW ---------------------
// 64 lanes read the row's 64 stored keys (top-2 per 256-col block), wave-min
// -> threshold -> ballot survivors -> exact fp32 distance per survivor ->
// best index (u64 key: ties to lowest index) -> write index + residual.
// r12: the winning k<bestk branch is WAVE-UNIFORM (p,c,k identical across
// lanes after the shfl reduce) -> carry the winning row's e0/e1 in registers
// and drop the final E[idx] re-read (-2KB/row, ~16MB total).
__global__ __launch_bounds__(256) void refine_kernel(
    const float* __restrict__ X, const float* __restrict__ E,
    const float* __restrict__ bestf, float* __restrict__ out)
{
    const int lane = threadIdx.x & 63, wave = threadIdx.x >> 6;
    const int b = blockIdx.x * 4 + wave;

    const float val = bestf[(size_t)b * 64 + lane];
    // decode this slot's candidate column: slot = cb*2 + j, cb = 256-col block
    const unsigned bits = __float_as_uint(val);
    const int cb = lane >> 1;
    const int colg = (bits >> 4) & 15, wn = (bits >> 2) & 3, ni = bits & 3;
    const int col = cb * 256 + wn * 64 + ni * 16 + colg;

    float mn = val;
    #pragma unroll
    for (int off = 1; off < 64; off <<= 1) mn = fminf(mn, __shfl_xor(mn, off));

    const float4* xr = (const float4*)(X + (size_t)b * Dn);
    const float4 x0 = xr[lane * 2], x1 = xr[lane * 2 + 1];

    u64 bestk = ~0ull;
    float4 be0, be1;                       // winning row's slice (wave-uniform upd)
    u64 mask = __ballot(val <= mn + WINDOW);
    while (mask) {
        const int s = __builtin_ctzll(mask);
        mask &= mask - 1;
        const int c = __shfl(col, s);
        const float4* er = (const float4*)(E + (size_t)c * Dn);
        const float4 e0 = er[lane * 2], e1 = er[lane * 2 + 1];
        float p = e0.x*(e0.x - 2.f*x0.x) + e0.y*(e0.y - 2.f*x0.y)
                + e0.z*(e0.z - 2.f*x0.z) + e0.w*(e0.w - 2.f*x0.w)
                + e1.x*(e1.x - 2.f*x1.x) + e1.y*(e1.y - 2.f*x1.y)
                + e1.z*(e1.z - 2.f*x1.z) + e1.w*(e1.w - 2.f*x1.w);
        #pragma unroll
        for (int off = 1; off < 64; off <<= 1) p += __shfl_xor(p, off);
        const u64 k = ((u64)fkey(p) << 32) | (u64)(unsigned int)c;
        if (k < bestk) { bestk = k; be0 = e0; be1 = e1; }
    }

    const int idx = (int)(unsigned int)(bestk & 0xFFFFFFFFull);
    if (lane == 0) out[b] = (float)idx;
    float4 r0, r1;
    r0.x = x0.x - be0.x; r0.y = x0.y - be0.y; r0.z = x0.z - be0.z; r0.w = x0.w - be0.w;
    r1.x = x1.x - be1.x; r1.y = x1.y - be1.y; r1.z = x1.z - be1.z; r1.w = x1.w - be1.w;
    float4* o = (float4*)(out + Bn + (size_t)b * Dn);
    o[lane * 2] = r0; o[lane * 2 + 1] = r1;
}

// ---------------- fallback (round-1 fp32 path, used only if ws too small) ----
#define KSPLIT 16
#define LDSW 132
__global__ __launch_bounds__(256, 2) void argmin_fp32(
    const float* __restrict__ X, const float* __restrict__ E,
    const float* __restrict__ esq, u64* __restrict__ best)
{
    __shared__ __align__(16) float Xs[16][LDSW];
    __shared__ __align__(16) float Es[16][LDSW];
    __shared__ u64 red[128][16];
    const int tid = threadIdx.x;
    const int tx = tid & 15, ty = tid >> 4;
    const int rowTile = blockIdx.x / KSPLIT;
    const int split   = blockIdx.x % KSPLIT;
    const int m0 = rowTile * 128;
    const int kbase = split * (Kn / KSPLIT);
    float bestv[8]; int besti[8];
    #pragma unroll
    for (int i = 0; i < 8; ++i) { bestv[i] = INFINITY; besti[i] = 0; }
    const int ldRow = tid >> 2, ldD = (tid & 3) * 4;
    for (int kt = 0; kt < (Kn / KSPLIT) / 128; ++kt) {
        const int k0 = kbase + kt * 128;
        float acc[8][8] = {};
        for (int dc = 0; dc < Dn / 16; ++dc) {
            const int d0 = dc * 16;
            float4 xa = *(const float4*)&X[(size_t)(m0 + ldRow)      * Dn + d0 + ldD];
            float4 xb = *(const float4*)&X[(size_t)(m0 + 64 + ldRow) * Dn + d0 + ldD];
            float4 ea = *(const float4*)&E[(size_t)(k0 + ldRow)      * Dn + d0 + ldD];
            float4 eb = *(const float4*)&E[(size_t)(k0 + 64 + ldRow) * Dn + d0 + ldD];
            __syncthreads();
            Xs[ldD+0][ldRow] = xa.x; Xs[ldD+1][ldRow] = xa.y;
            Xs[ldD+2][ldRow] = xa.z; Xs[ldD+3][ldRow] = xa.w;
            Xs[ldD+0][64+ldRow] = xb.x; Xs[ldD+1][64+ldRow] = xb.y;
            Xs[ldD+2][64+ldRow] = xb.z; Xs[ldD+3][64+ldRow] = xb.w;
            Es[ldD+0][ldRow] = ea.x; Es[ldD+1][ldRow] = ea.y;
            Es[ldD+2][ldRow] = ea.z; Es[ldD+3][ldRow] = ea.w;
            Es[ldD+0][64+ldRow] = eb.x; Es[ldD+1][64+ldRow] = eb.y;
            Es[ldD+2][64+ldRow] = eb.z; Es[ldD+3][64+ldRow] = eb.w;
            __syncthreads();
            #pragma unroll
            for (int d = 0; d < 16; ++d) {
                float a8[8], b8[8];
                *(float4*)&a8[0] = *(const float4*)&Xs[d][4*ty];
                *(float4*)&a8[4] = *(const float4*)&Xs[d][64 + 4*ty];
                *(float4*)&b8[0] = *(const float4*)&Es[d][4*tx];
                *(float4*)&b8[4] = *(const float4*)&Es[d][64 + 4*tx];
                #pragma unroll
                for (int i = 0; i < 8; ++i)
                    #pragma unroll
                    for (int j = 0; j < 8; ++j) acc[i][j] += a8[i] * b8[j];
            }
        }
        #pragma unroll
        for (int j = 0; j < 8; ++j) {
            const int c = k0 + ((j < 4) ? (4*tx + j) : (64 + 4*tx + (j - 4)));
            const float eq = esq[c];
            #pragma unroll
            for (int i = 0; i < 8; ++i) {
                float dval = eq - 2.0f * acc[i][j];
                if (dval < bestv[i]) { bestv[i] = dval; besti[i] = c; }
            }
        }
    }
    #pragma unroll
    for (int i = 0; i < 8; ++i) {
        int rloc = (i < 4) ? (4*ty + i) : (64 + 4*ty + (i - 4));
        red[rloc][tx] = ((u64)fkey(bestv[i]) << 32) | (u64)(unsigned int)besti[i];
    }
    __syncthreads();
    if (tid < 128) {
        u64 m = red[tid][0];
        #pragma unroll
        for (int t = 1; t < 16; ++t) { u64 v = red[tid][t]; if (v < m) m = v; }
        best[(size_t)(m0 + tid) * KSPLIT + split] = m;
    }
}

__global__ __launch_bounds__(256) void finalize_kernel(
    const float* __restrict__ X, const float* __restrict__ E,
    const u64* __restrict__ best, float* __restrict__ out, int nsplits)
{
    __shared__ int sidx[2];
    const int half = threadIdx.x >> 7;
    const int t    = threadIdx.x & 127;
    const int b    = blockIdx.x * 2 + half;
    if (t < 64) {
        u64 v = (t < nsplits) ? best[(size_t)b * nsplits + t] : ~0ull;
        #pragma unroll
        for (int off = 1; off < 64; off <<= 1) {
            u64 o = __shfl_xor(v, off);
            if (o < v) v = o;
        }
        if (t == 0) {
            int idx = (int)(unsigned int)(v & 0xFFFFFFFFull);
            sidx[half] = idx;
            out[b] = (float)idx;
        }
    }
    __syncthreads();
    const int idx = sidx[half];
    float4 x = ((const float4*)(X + (size_t)b * Dn))[t];
    float4 e = ((const float4*)(E + (size_t)idx * Dn))[t];
    float4 r; r.x = x.x - e.x; r.y = x.y - e.y; r.z = x.z - e.z; r.w = x.w - e.w;
    ((float4*)(out + Bn + (size_t)b * Dn))[t] = r;
}

extern "C" void kernel_launch(void* const* d_in, const int* in_sizes, int n_in,
                              void* d_out, int out_size, void* d_ws, size_t ws_size,
                              hipStream_t stream) {
    const float* X = (const float*)d_in[0];   // previous_residual [B, D]
    const float* E = (const float*)d_in[1];   // codebook_embeddings [K, D]
    float* out = (float*)d_out;               // [B] idx-as-float ++ [B*D] residual

    // fast-path ws: esq 32KB | Xh 8MB | Eh 8MB | bestf 2MB  (~18.3 MB)
    const size_t HB = (size_t)Bn * Dn * sizeof(_Float16);        // 8 MB
    const size_t BESTB = (size_t)Bn * 64 * sizeof(float);        // 2 MB
    const size_t NEED = 32768 + 2 * HB + BESTB;

    float* esq = (float*)d_ws;

    if (ws_size >= NEED) {
        _Float16* Xh = (_Float16*)((char*)d_ws + 32768);
        _Float16* Eh = (_Float16*)((char*)d_ws + 32768 + HB);
        float* bestf = (float*)((char*)d_ws + 32768 + 2 * HB);
        hipMemsetAsync((void*)esq, 0, Kn * sizeof(float), stream);
        convert_hi<<<2048, 256, 0, stream>>>(X, E, Xh, Eh, esq);
        argmin_hi<<<2048, 512, 0, stream>>>(Xh, Eh, esq, bestf);
        refine_kernel<<<Bn / 4, 256, 0, stream>>>(X, E, bestf, out);
    } else {
        u64* best = (u64*)((char*)d_ws + 32768);
        esq_kernel<<<Kn / 4, 256, 0, stream>>>(E, esq);
        argmin_fp32<<<(Bn / 128) * KSPLIT, 256, 0, stream>>>(X, E, esq, best);
        finalize_kernel<<<Bn / 2, 256, 0, stream>>>(X, E, best, out, KSPLIT);
    }
}

// Round 15
// 168.780 us; speedup vs baseline: 1.0457x; 1.0034x over previous
//
#include <hip/hip_runtime.h>

// Problem constants (fp32 RQ-VAE nearest-codebook step)
#define Bn 8192
#define Kn 8192
#define Dn 512
#define WINDOW 0.25f   // refine window: covers f16-noise + 8-bit mantissa packing

typedef _Float16 half8 __attribute__((ext_vector_type(8)));
typedef float floatx4 __attribute__((ext_vector_type(4)));
typedef unsigned long long u64;

// Order-preserving map float -> u32 (monotone under unsigned compare, finite inputs)
__device__ __forceinline__ unsigned int fkey(float f) {
    unsigned int u = __float_as_uint(f);
    return (u & 0x80000000u) ? ~u : (u | 0x80000000u);
}

// async global->LDS, 16B per lane (global_load_lds_dwordx4)
__device__ __forceinline__ void gld16(const _Float16* g, _Float16* l) {
    __builtin_amdgcn_global_load_lds(
        (const __attribute__((address_space(1))) unsigned int*)g,
        (__attribute__((address_space(3))) unsigned int*)l, 16, 0, 0);
}

// ---------------- kernel: e_sq (fallback path only) ----------------
__global__ __launch_bounds__(256) void esq_kernel(const float* __restrict__ E,
                                                  float* __restrict__ esq) {
    int wave = threadIdx.x >> 6;
    int lane = threadIdx.x & 63;
    int k = blockIdx.x * 4 + wave;
    const float4* row = (const float4*)(E + (size_t)k * Dn);
    float4 v0 = row[lane];
    float4 v1 = row[64 + lane];
    float s = v0.x*v0.x + v0.y*v0.y + v0.z*v0.z + v0.w*v0.w
            + v1.x*v1.x + v1.y*v1.y + v1.z*v1.z + v1.w*v1.w;
    #pragma unroll
    for (int off = 32; off > 0; off >>= 1) s += __shfl_down(s, off, 64);
    if (lane == 0) esq[k] = s;
}

// ---------------- kernel: fp32 -> f16 (hi), PACKED layout, + fused e_sq ------
// G[panel][chunk][slot]*8 halves, panel = 128 rows, chunk = 32 k-halves,
//   slot(row128, kq) = (row128>>6)*256 + ((row128>>4)&3)*64 + kq*16 + (row128&15)
// blocks [0,1024) pack X, [1024,2048) pack E (E blocks also atomicAdd e_sq
// partials; esq must be zeroed before launch).
// r11 LESSON: direct 16B stores all land inside one contiguous 8KB unit per
// block -> every 64B line fully covered -> NO coalescing loss (LDS-roundtrip
// "fix" regressed 5us). Keep direct stores.
__global__ __launch_bounds__(256) void convert_hi(
    const float* __restrict__ X, const float* __restrict__ E,
    _Float16* __restrict__ Xh, _Float16* __restrict__ Eh,
    float* __restrict__ esq)
{
    const bool isE = blockIdx.x >= 1024;
    const int pc = blockIdx.x & 1023;
    const int panel = pc >> 4;              // 64 panels of 128 rows
    const int chunk = pc & 15;              // 16 chunks of 32 halves
    const float* src = isE ? E : X;
    _Float16* dst = isE ? Eh : Xh;
    const int t = threadIdx.x;
    const int row = t >> 1;                 // [0,128)
    const int kh  = (t & 1) * 16;
    const float* p = &src[(size_t)(panel * 128 + row) * Dn + chunk * 32 + kh];
    float4 v[4];
    v[0] = *(const float4*)(p + 0);
    v[1] = *(const float4*)(p + 4);
    v[2] = *(const float4*)(p + 8);
    v[3] = *(const float4*)(p + 12);
    const int slotbase = ((row >> 6) << 8) + (((row >> 4) & 3) << 6) + (row & 15);
    #pragma unroll
    for (int j = 0; j < 2; ++j) {
        half8 h;
        #pragma unroll
        for (int q = 0; q < 2; ++q) {
            const float4 w = v[j * 2 + q];
            h[q*4+0]=(_Float16)w.x; h[q*4+1]=(_Float16)w.y;
            h[q*4+2]=(_Float16)w.z; h[q*4+3]=(_Float16)w.w;
        }
        const int kq = (t & 1) * 2 + j;
        const size_t off = ((size_t)(panel * 16 + chunk) * 512
                            + slotbase + kq * 16) * 8;
        *(half8*)&dst[off] = h;
    }
    if (isE) {
        float s = 0.f;
        #pragma unroll
        for (int i = 0; i < 4; ++i)
            s += v[i].x*v[i].x + v[i].y*v[i].y + v[i].z*v[i].z + v[i].w*v[i].w;
        s += __shfl_xor(s, 1);              // pair (kh=0, kh=16) -> 32-col partial
        if ((t & 1) == 0) atomicAdd(&esq[panel * 128 + row], s);
    }
}

// ---------------- kernel: hi-only MFMA, 128x256, A-LDS / B-direct-from-L2 ----
// d~(b,k) = e_sq[k] - 2*(xh.eh). Wave tile 64x64 (acc 4x4 = 64 AGPR), 8 waves
// (wm 2 x wn 4), __launch_bounds__(512,4) -> 128 unified regs -> 4 waves/SIMD
// = 16 waves/CU, 2 blocks/CU (r8 VERIFIED +15%).
// r12 MODEL (from r8/r10 counters): per dual-block interval 3450cyc, MFMA
// needs 1242 (36%=MfmaUtil), LDS port needs 2070 (reads 128KB + staging 48KB)
// -> sum 3312 ~= 3450: barrier phase-locks waves into read-burst/MFMA-burst
// convoys, LDS + MFMA SERIALIZE. Depth (r10 tri-buffer) was null -> only
// removing LDS traffic helps. FIX: B direct global->VGPR (bb[4]); B panels
// are L2-RESIDENT BY DESIGN (bx%8 swizzle -> 2MB Eh slice/XCD); correctness
// of B-direct proven in r6 (passed). r6's slowdown was its 2-waves/SIMD
// structure; now 16 waves/CU cover L2 latency. New interval budget: LDS
// 940cyc (A only), B-from-L2 ~1140 (separate port), MFMA 1242 -> ~55-75us.
// Queue discipline: bb issued BEFORE stageA(t+2) so pre-MFMA wait is
// vmcnt(1) (FIFO: retires bb, keeps staging in flight - never drains it).
__global__ __launch_bounds__(512, 4) void argmin_hi(
    const _Float16* __restrict__ Xh, const _Float16* __restrict__ Eh,
    const float* __restrict__ esq, float* __restrict__ bestf)
{
    __shared__ __align__(16) _Float16 sA[3][4096];      // [buf][128r x 32k] 24KB

    const int tid  = threadIdx.x;
    const int bid  = blockIdx.x;
    const int bx   = bid & 31;           // 32 col-blocks of 256 (bx%8 -> XCD set)
    const int by   = bid >> 5;           // 64 row-blocks of 128
    const int lane = tid & 63, wave = tid >> 6;
    const int wm   = wave >> 2;          // 0..1: 64-row half
    const int wn   = wave & 3;           // 0..3: 64-col quarter
    const int colg = lane & 15, quad = lane >> 4;
    const int la8  = lane * 8;

    const _Float16* gA = Xh + (size_t)by * 65536 + tid * 8;
    // per-wave B base in packed layout: panel (2bx + (wn>>1)), 64-col half (wn&1)
    const _Float16* gB = Eh + (size_t)(2 * bx + (wn >> 1)) * 65536
                            + (wn & 1) * 2048 + la8;

    auto stageA = [&](int t, int b) {
        gld16(gA + t * 4096, &sA[b][tid * 8]);
    };

    floatx4 acc[4][4];
    #pragma unroll
    for (int i = 0; i < 4; ++i)
        #pragma unroll
        for (int j = 0; j < 4; ++j) acc[i][j] = {0.f, 0.f, 0.f, 0.f};

    // prologue: A chunks 0,1 in flight (tri-buffer)
    stageA(0, 0);
    stageA(1, 1);

    #pragma unroll
    for (int t = 0; t < 16; ++t) {
        const int b = t % 3;
        // head: publish A chunk t (FIFO: retired once <=1 outstanding);
        // barrier also retires all waves' reads of buf (t+2)%3 from iter t-1
        if (t < 15) asm volatile("s_waitcnt vmcnt(1)" ::: "memory");
        else        asm volatile("s_waitcnt vmcnt(0)" ::: "memory");
        __builtin_amdgcn_s_barrier();

        // B fragments DIRECT from global (L2-resident panel) - issued FIRST
        half8 bb[4];
        #pragma unroll
        for (int ni = 0; ni < 4; ++ni)
            bb[ni] = *(const half8*)(gB + t * 4096 + ni * 512);
        // then stage A chunk t+2 (stays in flight through this iter's MFMA)
        if (t + 2 < 16) stageA(t + 2, (t + 2) % 3);

        const _Float16* A0 = &sA[b][wm * 2048 + la8];
        half8 a[4];
        #pragma unroll
        for (int mi = 0; mi < 4; ++mi) a[mi] = *(const half8*)&A0[mi * 512];

        __builtin_amdgcn_s_setprio(1);
        #pragma unroll
        for (int mi = 0; mi < 4; ++mi)
            #pragma unroll
            for (int ni = 0; ni < 4; ++ni)
                acc[mi][ni] = __builtin_amdgcn_mfma_f32_16x16x32_f16(
                    a[mi], bb[ni], acc[mi][ni], 0, 0, 0);
        __builtin_amdgcn_s_setprio(0);
    }

    // ---- epilogue: per-(mi,r) top-2 over the wave's 64 cols, then cross-wn
    // merge in LDS -> top-2 per 256-col block (encoding identical to r3/r8).
    // sm lives in sA[1] (4KB): t=15 read buf 0 -> disjoint/retired.
    float2* sm = (float2*)&sA[1][0];
    const int n0 = bx * 256 + wn * 64;
    float eqv[4];
    #pragma unroll
    for (int ni = 0; ni < 4; ++ni) eqv[ni] = esq[n0 + ni * 16 + colg];
    const unsigned ob_base = ((unsigned)colg << 4) | ((unsigned)wn << 2);

    #pragma unroll
    for (int mi = 0; mi < 4; ++mi)
        #pragma unroll
        for (int r = 0; r < 4; ++r) {
            float w1 = INFINITY, w2 = INFINITY;
            #pragma unroll
            for (int ni = 0; ni < 4; ++ni) {
                const float dv = eqv[ni] - 2.0f * acc[mi][ni][r];
                const float key = __uint_as_float(
                    (__float_as_uint(dv) & 0xFFFFFF00u) | (ob_base | (unsigned)ni));
                w2 = fminf(w2, fmaxf(w1, key));
                w1 = fminf(w1, key);
            }
            #pragma unroll
            for (int off = 1; off < 16; off <<= 1) {
                const float p1 = __shfl_xor(w1, off);
                const float p2 = __shfl_xor(w2, off);
                w2 = fminf(fmaxf(w1, p1), fminf(w2, p2));
                w1 = fminf(w1, p1);
            }
            if (colg == 0) {
                const int row128 = wm * 64 + mi * 16 + quad * 4 + r;
                float2 st; st.x = w1; st.y = w2;
                sm[row128 * 4 + wn] = st;
            }
        }
    __syncthreads();
    if (tid < 128) {
        float m1 = INFINITY, m2 = INFINITY;
        #pragma unroll
        for (int w = 0; w < 4; ++w) {
            const float2 p = sm[tid * 4 + w];
            m2 = fminf(fmaxf(m1, p.x), fminf(m2, p.y));
            m1 = fminf(m1, p.x);
        }
        float2 st; st.x = m1; st.y = m2;
        *(float2*)&bestf[(size_t)(by * 128 + tid) * 64 + bx * 2] = st;
    }
}

// ---------------- kernel: exact refine, ONE WAVE PER ROW ---------------------
// 64 lanes read the row's 64 stored keys (top-2 per 256-col block), wave-min
// -> threshold -> ballot survivors -> exact fp32 distance per survivor ->
// best index (u64 key: ties to lowest index) -> write index + residual.
// r12: winning k<bestk branch is wave-uniform -> carry winning row's e0/e1
// in registers, no final E[idx] re-read.
__global__ __launch_bounds__(256) void refine_kernel(
    const float* __restrict__ X, const float* __restrict__ E,
    const float* __restrict__ bestf, float* __restrict__ out)
{
    const int lane = threadIdx.x & 63, wave = threadIdx.x >> 6;
    const int b = blockIdx.x * 4 + wave;

    const float val = bestf[(size_t)b * 64 + lane];
    // decode this slot's candidate column: slot = cb*2 + j, cb = 256-col block
    const unsigned bits = __float_as_uint(val);
    const int cb = lane >> 1;
    const int colg = (bits >> 4) & 15, wn = (bits >> 2) & 3, ni = bits & 3;
    const int col = cb * 256 + wn * 64 + ni * 16 + colg;

    float mn = val;
    #pragma unroll
    for (int off = 1; off < 64; off <<= 1) mn = fminf(mn, __shfl_xor(mn, off));

    const float4* xr = (const float4*)(X + (size_t)b * Dn);
    const float4 x0 = xr[lane * 2], x1 = xr[lane * 2 + 1];

    u64 bestk = ~0ull;
    float4 be0, be1;                       // winning row's slice (wave-uniform upd)
    u64 mask = __ballot(val <= mn + WINDOW);
    while (mask) {
        const int s = __builtin_ctzll(mask);
        mask &= mask - 1;
        const int c = __shfl(col, s);
        const float4* er = (const float4*)(E + (size_t)c * Dn);
        const float4 e0 = er[lane * 2], e1 = er[lane * 2 + 1];
        float p = e0.x*(e0.x - 2.f*x0.x) + e0.y*(e0.y - 2.f*x0.y)
                + e0.z*(e0.z - 2.f*x0.z) + e0.w*(e0.w - 2.f*x0.w)
                + e1.x*(e1.x - 2.f*x1.x) + e1.y*(e1.y - 2.f*x1.y)
                + e1.z*(e1.z - 2.f*x1.z) + e1.w*(e1.w - 2.f*x1.w);
        #pragma unroll
        for (int off = 1; off < 64; off <<= 1) p += __shfl_xor(p, off);
        const u64 k = ((u64)fkey(p) << 32) | (u64)(unsigned int)c;
        if (k < bestk) { bestk = k; be0 = e0; be1 = e1; }
    }

    const int idx = (int)(unsigned int)(bestk & 0xFFFFFFFFull);
    if (lane == 0) out[b] = (float)idx;
    float4 r0, r1;
    r0.x = x0.x - be0.x; r0.y = x0.y - be0.y; r0.z = x0.z - be0.z; r0.w = x0.w - be0.w;
    r1.x = x1.x - be1.x; r1.y = x1.y - be1.y; r1.z = x1.z - be1.z; r1.w = x1.w - be1.w;
    float4* o = (float4*)(out + Bn + (size_t)b * Dn);
    o[lane * 2] = r0; o[lane * 2 + 1] = r1;
}

// ---------------- fallback (round-1 fp32 path, used only if ws too small) ----
#define KSPLIT 16
#define LDSW 132
__global__ __launch_bounds__(256, 2) void argmin_fp32(
    const float* __restrict__ X, const float* __restrict__ E,
    const float* __restrict__ esq, u64* __restrict__ best)
{
    __shared__ __align__(16) float Xs[16][LDSW];
    __shared__ __align__(16) float Es[16][LDSW];
    __shared__ u64 red[128][16];
    const int tid = threadIdx.x;
    const int tx = tid & 15, ty = tid >> 4;
    const int rowTile = blockIdx.x / KSPLIT;
    const int split   = blockIdx.x % KSPLIT;
    const int m0 = rowTile * 128;
    const int kbase = split * (Kn / KSPLIT);
    float bestv[8]; int besti[8];
    #pragma unroll
    for (int i = 0; i < 8; ++i) { bestv[i] = INFINITY; besti[i] = 0; }
    const int ldRow = tid >> 2, ldD = (tid & 3) * 4;
    for (int kt = 0; kt < (Kn / KSPLIT) / 128; ++kt) {
        const int k0 = kbase + kt * 128;
        float acc[8][8] = {};
        for (int dc = 0; dc < Dn / 16; ++dc) {
            const int d0 = dc * 16;
            float4 xa = *(const float4*)&X[(size_t)(m0 + ldRow)      * Dn + d0 + ldD];
            float4 xb = *(const float4*)&X[(size_t)(m0 + 64 + ldRow) * Dn + d0 + ldD];
            float4 ea = *(const float4*)&E[(size_t)(k0 + ldRow)      * Dn + d0 + ldD];
            float4 eb = *(const float4*)&E[(size_t)(k0 + 64 + ldRow) * Dn + d0 + ldD];
            __syncthreads();
            Xs[ldD+0][ldRow] = xa.x; Xs[ldD+1][ldRow] = xa.y;
            Xs[ldD+2][ldRow] = xa.z; Xs[ldD+3][ldRow] = xa.w;
            Xs[ldD+0][64+ldRow] = xb.x; Xs[ldD+1][64+ldRow] = xb.y;
            Xs[ldD+2][64+ldRow] = xb.z; Xs[ldD+3][64+ldRow] = xb.w;
            Es[ldD+0][ldRow] = ea.x; Es[ldD+1][ldRow] = ea.y;
            Es[ldD+2][ldRow] = ea.z; Es[ldD+3][ldRow] = ea.w;
            Es[ldD+0][64+ldRow] = eb.x; Es[ldD+1][64+ldRow] = eb.y;
            Es[ldD+2][64+ldRow] = eb.z; Es[ldD+3][64+ldRow] = eb.w;
            __syncthreads();
            #pragma unroll
            for (int d = 0; d < 16; ++d) {
                float a8[8], b8[8];
                *(float4*)&a8[0] = *(const float4*)&Xs[d][4*ty];
                *(float4*)&a8[4] = *(const float4*)&Xs[d][64 + 4*ty];
                *(float4*)&b8[0] = *(const float4*)&Es[d][4*tx];
                *(float4*)&b8[4] = *(const float4*)&Es[d][64 + 4*tx];
                #pragma unroll
                for (int i = 0; i < 8; ++i)
                    #pragma unroll
                    for (int j = 0; j < 8; ++j) acc[i][j] += a8[i] * b8[j];
            }
        }
        #pragma unroll
        for (int j = 0; j < 8; ++j) {
            const int c = k0 + ((j < 4) ? (4*tx + j) : (64 + 4*tx + (j - 4)));
            const float eq = esq[c];
            #pragma unroll
            for (int i = 0; i < 8; ++i) {
                float dval = eq - 2.0f * acc[i][j];
                if (dval < bestv[i]) { bestv[i] = dval; besti[i] = c; }
            }
        }
    }
    #pragma unroll
    for (int i = 0; i < 8; ++i) {
        int rloc = (i < 4) ? (4*ty + i) : (64 + 4*ty + (i - 4));
        red[rloc][tx] = ((u64)fkey(bestv[i]) << 32) | (u64)(unsigned int)besti[i];
    }
    __syncthreads();
    if (tid < 128) {
        u64 m = red[tid][0];
        #pragma unroll
        for (int t = 1; t < 16; ++t) { u64 v = red[tid][t]; if (v < m) m = v; }
        best[(size_t)(m0 + tid) * KSPLIT + split] = m;
    }
}

__global__ __launch_bounds__(256) void finalize_kernel(
    const float* __restrict__ X, const float* __restrict__ E,
    const u64* __restrict__ best, float* __restrict__ out, int nsplits)
{
    __shared__ int sidx[2];
    const int half = threadIdx.x >> 7;
    const int t    = threadIdx.x & 127;
    const int b    = blockIdx.x * 2 + half;
    if (t < 64) {
        u64 v = (t < nsplits) ? best[(size_t)b * nsplits + t] : ~0ull;
        #pragma unroll
        for (int off = 1; off < 64; off <<= 1) {
            u64 o = __shfl_xor(v, off);
            if (o < v) v = o;
        }
        if (t == 0) {
            int idx = (int)(unsigned int)(v & 0xFFFFFFFFull);
            sidx[half] = idx;
            out[b] = (float)idx;
        }
    }
    __syncthreads();
    const int idx = sidx[half];
    float4 x = ((const float4*)(X + (size_t)b * Dn))[t];
    float4 e = ((const float4*)(E + (size_t)idx * Dn))[t];
    float4 r; r.x = x.x - e.x; r.y = x.y - e.y; r.z = x.z - e.z; r.w = x.w - e.w;
    ((float4*)(out + Bn + (size_t)b * Dn))[t] = r;
}

extern "C" void kernel_launch(void* const* d_in, const int* in_sizes, int n_in,
                              void* d_out, int out_size, void* d_ws, size_t ws_size,
                              hipStream_t stream) {
    const float* X = (const float*)d_in[0];   // previous_residual [B, D]
    const float* E = (const float*)d_in[1];   // codebook_embeddings [K, D]
    float* out = (float*)d_out;               // [B] idx-as-float ++ [B*D] residual

    // fast-path ws: esq 32KB | Xh 8MB | Eh 8MB | bestf 2MB  (~18.3 MB)
    const size_t HB = (size_t)Bn * Dn * sizeof(_Float16);        // 8 MB
    const size_t BESTB = (size_t)Bn * 64 * sizeof(float);        // 2 MB
    const size_t NEED = 32768 + 2 * HB + BESTB;

    float* esq = (float*)d_ws;

    if (ws_size >= NEED) {
        _Float16* Xh = (_Float16*)((char*)d_ws + 32768);
        _Float16* Eh = (_Float16*)((char*)d_ws + 32768 + HB);
        float* bestf = (float*)((char*)d_ws + 32768 + 2 * HB);
        hipMemsetAsync((void*)esq, 0, Kn * sizeof(float), stream);
        convert_hi<<<2048, 256, 0, stream>>>(X, E, Xh, Eh, esq);
        argmin_hi<<<2048, 512, 0, stream>>>(Xh, Eh, esq, bestf);
        refine_kernel<<<Bn / 4, 256, 0, stream>>>(X, E, bestf, out);
    } else {
        u64* best = (u64*)((char*)d_ws + 32768);
        esq_kernel<<<Kn / 4, 256, 0, stream>>>(E, esq);
        argmin_fp32<<<(Bn / 128) * KSPLIT, 256, 0, stream>>>(X, E, esq, best);
        finalize_kernel<<<Bn / 2, 256, 0, stream>>>(X, E, best, out, KSPLIT);
    }
}

// Round 16
// 167.806 us; speedup vs baseline: 1.0517x; 1.0058x over previous
//
#include <hip/hip_runtime.h>

// Problem constants (fp32 RQ-VAE nearest-codebook step)
#define Bn 8192
#define Kn 8192
#define Dn 512
#define WINDOW 0.25f   // refine window: covers f16-noise + 8-bit mantissa packing

typedef _Float16 half8 __attribute__((ext_vector_type(8)));
typedef float floatx4 __attribute__((ext_vector_type(4)));
typedef unsigned long long u64;

// Order-preserving map float -> u32 (monotone under unsigned compare, finite inputs)
__device__ __forceinline__ unsigned int fkey(float f) {
    unsigned int u = __float_as_uint(f);
    return (u & 0x80000000u) ? ~u : (u | 0x80000000u);
}

// async global->LDS, 16B per lane (global_load_lds_dwordx4)
__device__ __forceinline__ void gld16(const _Float16* g, _Float16* l) {
    __builtin_amdgcn_global_load_lds(
        (const __attribute__((address_space(1))) unsigned int*)g,
        (__attribute__((address_space(3))) unsigned int*)l, 16, 0, 0);
}

// ---------------- kernel: e_sq (fallback path only) ----------------
__global__ __launch_bounds__(256) void esq_kernel(const float* __restrict__ E,
                                                  float* __restrict__ esq) {
    int wave = threadIdx.x >> 6;
    int lane = threadIdx.x & 63;
    int k = blockIdx.x * 4 + wave;
    const float4* row = (const float4*)(E + (size_t)k * Dn);
    float4 v0 = row[lane];
    float4 v1 = row[64 + lane];
    float s = v0.x*v0.x + v0.y*v0.y + v0.z*v0.z + v0.w*v0.w
            + v1.x*v1.x + v1.y*v1.y + v1.z*v1.z + v1.w*v1.w;
    #pragma unroll
    for (int off = 32; off > 0; off >>= 1) s += __shfl_down(s, off, 64);
    if (lane == 0) esq[k] = s;
}

// ---------------- kernel: fp32 -> f16 (hi), PACKED layout, + fused e_sq ------
// G[panel][chunk][slot]*8 halves, panel = 128 rows, chunk = 32 k-halves,
//   slot(row128, kq) = (row128>>6)*256 + ((row128>>4)&3)*64 + kq*16 + (row128&15)
// blocks [0,1024) pack X, [1024,2048) pack E (E blocks also atomicAdd e_sq
// partials; esq must be zeroed before launch).
// r11 LESSON: direct 16B stores all land inside one contiguous 8KB unit per
// block -> fully covered 64B lines -> no coalescing loss. Keep direct stores.
__global__ __launch_bounds__(256) void convert_hi(
    const float* __restrict__ X, const float* __restrict__ E,
    _Float16* __restrict__ Xh, _Float16* __restrict__ Eh,
    float* __restrict__ esq)
{
    const bool isE = blockIdx.x >= 1024;
    const int pc = blockIdx.x & 1023;
    const int panel = pc >> 4;              // 64 panels of 128 rows
    const int chunk = pc & 15;              // 16 chunks of 32 halves
    const float* src = isE ? E : X;
    _Float16* dst = isE ? Eh : Xh;
    const int t = threadIdx.x;
    const int row = t >> 1;                 // [0,128)
    const int kh  = (t & 1) * 16;
    const float* p = &src[(size_t)(panel * 128 + row) * Dn + chunk * 32 + kh];
    float4 v[4];
    v[0] = *(const float4*)(p + 0);
    v[1] = *(const float4*)(p + 4);
    v[2] = *(const float4*)(p + 8);
    v[3] = *(const float4*)(p + 12);
    const int slotbase = ((row >> 6) << 8) + (((row >> 4) & 3) << 6) + (row & 15);
    #pragma unroll
    for (int j = 0; j < 2; ++j) {
        half8 h;
        #pragma unroll
        for (int q = 0; q < 2; ++q) {
            const float4 w = v[j * 2 + q];
            h[q*4+0]=(_Float16)w.x; h[q*4+1]=(_Float16)w.y;
            h[q*4+2]=(_Float16)w.z; h[q*4+3]=(_Float16)w.w;
        }
        const int kq = (t & 1) * 2 + j;
        const size_t off = ((size_t)(panel * 16 + chunk) * 512
                            + slotbase + kq * 16) * 8;
        *(half8*)&dst[off] = h;
    }
    if (isE) {
        float s = 0.f;
        #pragma unroll
        for (int i = 0; i < 4; ++i)
            s += v[i].x*v[i].x + v[i].y*v[i].y + v[i].z*v[i].z + v[i].w*v[i].w;
        s += __shfl_xor(s, 1);              // pair (kh=0, kh=16) -> 32-col partial
        if ((t & 1) == 0) atomicAdd(&esq[panel * 128 + row], s);
    }
}

// ---------------- kernel: hi-only MFMA, 128x256, A-LDS(6-slot)/B-direct ------
// d~(b,k) = e_sq[k] - 2*(xh.eh). Wave tile 64x64 (acc 4x4), 8 waves (wm2 x
// wn4), __launch_bounds__(512,4) -> 128 unified regs -> 4 waves/SIMD, 2
// blocks/CU (r8 +15%). r15 VERIFIED: B-direct-from-L2 85.5us, MfmaUtil 35%,
// interval budget MFMA 1242 + A-LDS 940 + B-L2 1170 ~= measured 3206 ->
// still ADDITIVE: the 16 barriers phase-lock waves into load-burst/MFMA-burst
// convoys (depth null r10, traffic removal paid r15). FIX: HALVE BARRIER
// COUNT - 6 A-slots (48KB, x2 blocks = 96KB <= 160 -> occupancy kept), 2
// chunks per barrier interval. Order per iter: {vmcnt(2); barrier;
// bb(c0),bb(c1) THEN stage(2i+4),(2i+5)} -> FIFO waits: MFMA c0 at vmcnt<=6,
// MFMA c1 at vmcnt<=2, both keep the 2 fresh stages in flight; head vmcnt(2)
// is a no-op in steady state (publication only). Stage targets slots read in
// iter i-1, separated by the head barrier -> race-free.
__global__ __launch_bounds__(512, 4) void argmin_hi(
    const _Float16* __restrict__ Xh, const _Float16* __restrict__ Eh,
    const float* __restrict__ esq, float* __restrict__ bestf)
{
    __shared__ __align__(16) _Float16 sA[6][4096];      // [slot][128r x 32k] 48KB

    const int tid  = threadIdx.x;
    const int bid  = blockIdx.x;
    const int bx   = bid & 31;           // 32 col-blocks of 256 (bx%8 -> XCD set)
    const int by   = bid >> 5;           // 64 row-blocks of 128
    const int lane = tid & 63, wave = tid >> 6;
    const int wm   = wave >> 2;          // 0..1: 64-row half
    const int wn   = wave & 3;           // 0..3: 64-col quarter
    const int colg = lane & 15, quad = lane >> 4;
    const int la8  = lane * 8;

    const _Float16* gA = Xh + (size_t)by * 65536 + tid * 8;
    // per-wave B base in packed layout: panel (2bx + (wn>>1)), 64-col half (wn&1)
    const _Float16* gB = Eh + (size_t)(2 * bx + (wn >> 1)) * 65536
                            + (wn & 1) * 2048 + la8;

    auto stageA = [&](int t, int s) {
        gld16(gA + t * 4096, &sA[s][tid * 8]);
    };

    floatx4 acc[4][4];
    #pragma unroll
    for (int i = 0; i < 4; ++i)
        #pragma unroll
        for (int j = 0; j < 4; ++j) acc[i][j] = {0.f, 0.f, 0.f, 0.f};

    // prologue: A chunks 0..3 in flight (slots 0..3)
    stageA(0, 0); stageA(1, 1); stageA(2, 2); stageA(3, 3);

    #pragma unroll
    for (int i = 0; i < 8; ++i) {
        const int c0 = 2 * i, c1 = 2 * i + 1;
        const int s0 = c0 % 6, s1 = c1 % 6;
        // head: publish chunks c0,c1 (steady state: already retired by prior
        // iter's MFMA waits; i=0: drains st0,st1, keeps st2,st3)
        asm volatile("s_waitcnt vmcnt(2)" ::: "memory");
        __builtin_amdgcn_s_barrier();

        // B fragments for BOTH chunks first (FIFO ahead of stages)
        half8 bb0[4], bb1[4];
        #pragma unroll
        for (int ni = 0; ni < 4; ++ni)
            bb0[ni] = *(const half8*)(gB + c0 * 4096 + ni * 512);
        #pragma unroll
        for (int ni = 0; ni < 4; ++ni)
            bb1[ni] = *(const half8*)(gB + c1 * 4096 + ni * 512);
        // then stage chunks c0+4, c1+4 (slots read in iter i-1; barrier above
        // retired their readers)
        if (c0 + 4 < 16) stageA(c0 + 4, (c0 + 4) % 6);
        if (c1 + 4 < 16) stageA(c1 + 4, (c1 + 4) % 6);

        const _Float16* A0 = &sA[s0][wm * 2048 + la8];
        half8 a[4];
        #pragma unroll
        for (int mi = 0; mi < 4; ++mi) a[mi] = *(const half8*)&A0[mi * 512];
        __builtin_amdgcn_s_setprio(1);
        #pragma unroll
        for (int mi = 0; mi < 4; ++mi)
            #pragma unroll
            for (int ni = 0; ni < 4; ++ni)
                acc[mi][ni] = __builtin_amdgcn_mfma_f32_16x16x32_f16(
                    a[mi], bb0[ni], acc[mi][ni], 0, 0, 0);
        __builtin_amdgcn_s_setprio(0);

        const _Float16* A1 = &sA[s1][wm * 2048 + la8];
        #pragma unroll
        for (int mi = 0; mi < 4; ++mi) a[mi] = *(const half8*)&A1[mi * 512];
        __builtin_amdgcn_s_setprio(1);
        #pragma unroll
        for (int mi = 0; mi < 4; ++mi)
            #pragma unroll
            for (int ni = 0; ni < 4; ++ni)
                acc[mi][ni] = __builtin_amdgcn_mfma_f32_16x16x32_f16(
                    a[mi], bb1[ni], acc[mi][ni], 0, 0, 0);
        __builtin_amdgcn_s_setprio(0);
    }

    // ---- epilogue: per-(mi,r) top-2 over the wave's 64 cols, then cross-wn
    // merge in LDS -> top-2 per 256-col block (encoding identical to r3/r8).
    // sm in sA[0] (4KB): slots 0,1 last read in iter 6, retired by iter 7's
    // head barrier; final iter reads slots 2,3 only -> disjoint.
    float2* sm = (float2*)&sA[0][0];
    const int n0 = bx * 256 + wn * 64;
    float eqv[4];
    #pragma unroll
    for (int ni = 0; ni < 4; ++ni) eqv[ni] = esq[n0 + ni * 16 + colg];
    const unsigned ob_base = ((unsigned)colg << 4) | ((unsigned)wn << 2);

    #pragma unroll
    for (int mi = 0; mi < 4; ++mi)
        #pragma unroll
        for (int r = 0; r < 4; ++r) {
            float w1 = INFINITY, w2 = INFINITY;
            #pragma unroll
            for (int ni = 0; ni < 4; ++ni) {
                const float dv = eqv[ni] - 2.0f * acc[mi][ni][r];
                const float key = __uint_as_float(
                    (__float_as_uint(dv) & 0xFFFFFF00u) | (ob_base | (unsigned)ni));
                w2 = fminf(w2, fmaxf(w1, key));
                w1 = fminf(w1, key);
            }
            #pragma unroll
            for (int off = 1; off < 16; off <<= 1) {
                const float p1 = __shfl_xor(w1, off);
                const float p2 = __shfl_xor(w2, off);
                w2 = fminf(fmaxf(w1, p1), fminf(w2, p2));
                w1 = fminf(w1, p1);
            }
            if (colg == 0) {
                const int row128 = wm * 64 + mi * 16 + quad * 4 + r;
                float2 st; st.x = w1; st.y = w2;
                sm[row128 * 4 + wn] = st;
            }
        }
    __syncthreads();
    if (tid < 128) {
        float m1 = INFINITY, m2 = INFINITY;
        #pragma unroll
        for (int w = 0; w < 4; ++w) {
            const float2 p = sm[tid * 4 + w];
            m2 = fminf(fmaxf(m1, p.x), fminf(m2, p.y));
            m1 = fminf(m1, p.x);
        }
        float2 st; st.x = m1; st.y = m2;
        *(float2*)&bestf[(size_t)(by * 128 + tid) * 64 + bx * 2] = st;
    }
}

// ---------------- kernel: exact refine, ONE WAVE PER ROW ---------------------
// 64 lanes read the row's 64 stored keys (top-2 per 256-col block), wave-min
// -> threshold -> ballot survivors -> exact fp32 distance per survivor ->
// best index (u64 key: ties to lowest index) -> write index + residual.
// r12: winning k<bestk branch is wave-uniform -> carry winning row's e0/e1
// in registers, no final E[idx] re-read.
__global__ __launch_bounds__(256) void refine_kernel(
    const float* __restrict__ X, const float* __restrict__ E,
    const float* __restrict__ bestf, float* __restrict__ out)
{
    const int lane = threadIdx.x & 63, wave = threadIdx.x >> 6;
    const int b = blockIdx.x * 4 + wave;

    const float val = bestf[(size_t)b * 64 + lane];
    // decode this slot's candidate column: slot = cb*2 + j, cb = 256-col block
    const unsigned bits = __float_as_uint(val);
    const int cb = lane >> 1;
    const int colg = (bits >> 4) & 15, wn = (bits >> 2) & 3, ni = bits & 3;
    const int col = cb * 256 + wn * 64 + ni * 16 + colg;

    float mn = val;
    #pragma unroll
    for (int off = 1; off < 64; off <<= 1) mn = fminf(mn, __shfl_xor(mn, off));

    const float4* xr = (const float4*)(X + (size_t)b * Dn);
    const float4 x0 = xr[lane * 2], x1 = xr[lane * 2 + 1];

    u64 bestk = ~0ull;
    float4 be0, be1;                       // winning row's slice (wave-uniform upd)
    u64 mask = __ballot(val <= mn + WINDOW);
    while (mask) {
        const int s = __builtin_ctzll(mask);
        mask &= mask - 1;
        const int c = __shfl(col, s);
        const float4* er = (const float4*)(E + (size_t)c * Dn);
        const float4 e0 = er[lane * 2], e1 = er[lane * 2 + 1];
        float p = e0.x*(e0.x - 2.f*x0.x) + e0.y*(e0.y - 2.f*x0.y)
                + e0.z*(e0.z - 2.f*x0.z) + e0.w*(e0.w - 2.f*x0.w)
                + e1.x*(e1.x - 2.f*x1.x) + e1.y*(e1.y - 2.f*x1.y)
                + e1.z*(e1.z - 2.f*x1.z) + e1.w*(e1.w - 2.f*x1.w);
        #pragma unroll
        for (int off = 1; off < 64; off <<= 1) p += __shfl_xor(p, off);
        const u64 k = ((u64)fkey(p) << 32) | (u64)(unsigned int)c;
        if (k < bestk) { bestk = k; be0 = e0; be1 = e1; }
    }

    const int idx = (int)(unsigned int)(bestk & 0xFFFFFFFFull);
    if (lane == 0) out[b] = (float)idx;
    float4 r0, r1;
    r0.x = x0.x - be0.x; r0.y = x0.y - be0.y; r0.z = x0.z - be0.z; r0.w = x0.w - be0.w;
    r1.x = x1.x - be1.x; r1.y = x1.y - be1.y; r1.z = x1.z - be1.z; r1.w = x1.w - be1.w;
    float4* o = (float4*)(out + Bn + (size_t)b * Dn);
    o[lane * 2] = r0; o[lane * 2 + 1] = r1;
}

// ---------------- fallback (round-1 fp32 path, used only if ws too small) ----
#define KSPLIT 16
#define LDSW 132
__global__ __launch_bounds__(256, 2) void argmin_fp32(
    const float* __restrict__ X, const float* __restrict__ E,
    const float* __restrict__ esq, u64* __restrict__ best)
{
    __shared__ __align__(16) float Xs[16][LDSW];
    __shared__ __align__(16) float Es[16][LDSW];
    __shared__ u64 red[128][16];
    const int tid = threadIdx.x;
    const int tx = tid & 15, ty = tid >> 4;
    const int rowTile = blockIdx.x / KSPLIT;
    const int split   = blockIdx.x % KSPLIT;
    const int m0 = rowTile * 128;
    const int kbase = split * (Kn / KSPLIT);
    float bestv[8]; int besti[8];
    #pragma unroll
    for (int i = 0; i < 8; ++i) { bestv[i] = INFINITY; besti[i] = 0; }
    const int ldRow = tid >> 2, ldD = (tid & 3) * 4;
    for (int kt = 0; kt < (Kn / KSPLIT) / 128; ++kt) {
        const int k0 = kbase + kt * 128;
        float acc[8][8] = {};
        for (int dc = 0; dc < Dn / 16; ++dc) {
            const int d0 = dc * 16;
            float4 xa = *(const float4*)&X[(size_t)(m0 + ldRow)      * Dn + d0 + ldD];
            float4 xb = *(const float4*)&X[(size_t)(m0 + 64 + ldRow) * Dn + d0 + ldD];
            float4 ea = *(const float4*)&E[(size_t)(k0 + ldRow)      * Dn + d0 + ldD];
            float4 eb = *(const float4*)&E[(size_t)(k0 + 64 + ldRow) * Dn + d0 + ldD];
            __syncthreads();
            Xs[ldD+0][ldRow] = xa.x; Xs[ldD+1][ldRow] = xa.y;
            Xs[ldD+2][ldRow] = xa.z; Xs[ldD+3][ldRow] = xa.w;
            Xs[ldD+0][64+ldRow] = xb.x; Xs[ldD+1][64+ldRow] = xb.y;
            Xs[ldD+2][64+ldRow] = xb.z; Xs[ldD+3][64+ldRow] = xb.w;
            Es[ldD+0][ldRow] = ea.x; Es[ldD+1][ldRow] = ea.y;
            Es[ldD+2][ldRow] = ea.z; Es[ldD+3][ldRow] = ea.w;
            Es[ldD+0][64+ldRow] = eb.x; Es[ldD+1][64+ldRow] = eb.y;
            Es[ldD+2][64+ldRow] = eb.z; Es[ldD+3][64+ldRow] = eb.w;
            __syncthreads();
            #pragma unroll
            for (int d = 0; d < 16; ++d) {
                float a8[8], b8[8];
                *(float4*)&a8[0] = *(const float4*)&Xs[d][4*ty];
                *(float4*)&a8[4] = *(const float4*)&Xs[d][64 + 4*ty];
                *(float4*)&b8[0] = *(const float4*)&Es[d][4*tx];
                *(float4*)&b8[4] = *(const float4*)&Es[d][64 + 4*tx];
                #pragma unroll
                for (int i = 0; i < 8; ++i)
                    #pragma unroll
                    for (int j = 0; j < 8; ++j) acc[i][j] += a8[i] * b8[j];
            }
        }
        #pragma unroll
        for (int j = 0; j < 8; ++j) {
            const int c = k0 + ((j < 4) ? (4*tx + j) : (64 + 4*tx + (j - 4)));
            const float eq = esq[c];
            #pragma unroll
            for (int i = 0; i < 8; ++i) {
                float dval = eq - 2.0f * acc[i][j];
                if (dval < bestv[i]) { bestv[i] = dval; besti[i] = c; }
            }
        }
    }
    #pragma unroll
    for (int i = 0; i < 8; ++i) {
        int rloc = (i < 4) ? (4*ty + i) : (64 + 4*ty + (i - 4));
        red[rloc][tx] = ((u64)fkey(bestv[i]) << 32) | (u64)(unsigned int)besti[i];
    }
    __syncthreads();
    if (tid < 128) {
        u64 m = red[tid][0];
        #pragma unroll
        for (int t = 1; t < 16; ++t) { u64 v = red[tid][t]; if (v < m) m = v; }
        best[(size_t)(m0 + tid) * KSPLIT + split] = m;
    }
}

__global__ __launch_bounds__(256) void finalize_kernel(
    const float* __restrict__ X, const float* __restrict__ E,
    const u64* __restrict__ best, float* __restrict__ out, int nsplits)
{
    __shared__ int sidx[2];
    const int half = threadIdx.x >> 7;
    const int t    = threadIdx.x & 127;
    const int b    = blockIdx.x * 2 + half;
    if (t < 64) {
        u64 v = (t < nsplits) ? best[(size_t)b * nsplits + t] : ~0ull;
        #pragma unroll
        for (int off = 1; off < 64; off <<= 1) {
            u64 o = __shfl_xor(v, off);
            if (o < v) v = o;
        }
        if (t == 0) {
            int idx = (int)(unsigned int)(v & 0xFFFFFFFFull);
            sidx[half] = idx;
            out[b] = (float)idx;
        }
    }
    __syncthreads();
    const int idx = sidx[half];
    float4 x = ((const float4*)(X + (size_t)b * Dn))[t];
    float4 e = ((const float4*)(E + (size_t)idx * Dn))[t];
    float4 r; r.x = x.x - e.x; r.y = x.y - e.y; r.z = x.z - e.z; r.w = x.w - e.w;
    ((float4*)(out + Bn + (size_t)b * Dn))[t] = r;
}

extern "C" void kernel_launch(void* const* d_in, const int* in_sizes, int n_in,
                              void* d_out, int out_size, void* d_ws, size_t ws_size,
                              hipStream_t stream) {
    const float* X = (const float*)d_in[0];   // previous_residual [B, D]
    const float* E = (const float*)d_in[1];   // codebook_embeddings [K, D]
    float* out = (float*)d_out;               // [B] idx-as-float ++ [B*D] residual

    // fast-path ws: esq 32KB | Xh 8MB | Eh 8MB | bestf 2MB  (~18.3 MB)
    const size_t HB = (size_t)Bn * Dn * sizeof(_Float16);        // 8 MB
    const size_t BESTB = (size_t)Bn * 64 * sizeof(float);        // 2 MB
    const size_t NEED = 32768 + 2 * HB + BESTB;

    float* esq = (float*)d_ws;

    if (ws_size >= NEED) {
        _Float16* Xh = (_Float16*)((char*)d_ws + 32768);
        _Float16* Eh = (_Float16*)((char*)d_ws + 32768 + HB);
        float* bestf = (float*)((char*)d_ws + 32768 + 2 * HB);
        hipMemsetAsync((void*)esq, 0, Kn * sizeof(float), stream);
        convert_hi<<<2048, 256, 0, stream>>>(X, E, Xh, Eh, esq);
        argmin_hi<<<2048, 512, 0, stream>>>(Xh, Eh, esq, bestf);
        refine_kernel<<<Bn / 4, 256, 0, stream>>>(X, E, bestf, out);
    } else {
        u64* best = (u64*)((char*)d_ws + 32768);
        esq_kernel<<<Kn / 4, 256, 0, stream>>>(E, esq);
        argmin_fp32<<<(Bn / 128) * KSPLIT, 256, 0, stream>>>(X, E, esq, best);
        finalize_kernel<<<Bn / 2, 256, 0, stream>>>(X, E, best, out, KSPLIT);
    }
}

// Round 17
// 167.495 us; speedup vs baseline: 1.0537x; 1.0019x over previous
//
#include <hip/hip_runtime.h>

// Problem constants (fp32 RQ-VAE nearest-codebook step)
#define Bn 8192
#define Kn 8192
#define Dn 512
#define WINDOW 0.25f   // refine window: covers f16-noise + 8-bit mantissa packing

typedef _Float16 half8 __attribute__((ext_vector_type(8)));
typedef float floatx4 __attribute__((ext_vector_type(4)));
typedef unsigned long long u64;

// Order-preserving map float -> u32 (monotone under unsigned compare, finite inputs)
__device__ __forceinline__ unsigned int fkey(float f) {
    unsigned int u = __float_as_uint(f);
    return (u & 0x80000000u) ? ~u : (u | 0x80000000u);
}

// ---------------- kernel: e_sq (fallback path only) ----------------
__global__ __launch_bounds__(256) void esq_kernel(const float* __restrict__ E,
                                                  float* __restrict__ esq) {
    int wave = threadIdx.x >> 6;
    int lane = threadIdx.x & 63;
    int k = blockIdx.x * 4 + wave;
    const float4* row = (const float4*)(E + (size_t)k * Dn);
    float4 v0 = row[lane];
    float4 v1 = row[64 + lane];
    float s = v0.x*v0.x + v0.y*v0.y + v0.z*v0.z + v0.w*v0.w
            + v1.x*v1.x + v1.y*v1.y + v1.z*v1.z + v1.w*v1.w;
    #pragma unroll
    for (int off = 32; off > 0; off >>= 1) s += __shfl_down(s, off, 64);
    if (lane == 0) esq[k] = s;
}

// ---------------- kernel: fp32 -> f16 (hi), PACKED layout, + fused e_sq ------
// G[panel][chunk][slot]*8 halves, panel = 128 rows, chunk = 32 k-halves,
//   slot(row128, kq) = (row128>>6)*256 + ((row128>>4)&3)*64 + kq*16 + (row128&15)
// blocks [0,1024) pack X, [1024,2048) pack E (E blocks also atomicAdd e_sq
// partials; esq must be zeroed before launch).
// r11 LESSON: direct 16B stores all land inside one contiguous 8KB unit per
// block -> fully covered 64B lines -> no coalescing loss. Keep direct stores.
__global__ __launch_bounds__(256) void convert_hi(
    const float* __restrict__ X, const float* __restrict__ E,
    _Float16* __restrict__ Xh, _Float16* __restrict__ Eh,
    float* __restrict__ esq)
{
    const bool isE = blockIdx.x >= 1024;
    const int pc = blockIdx.x & 1023;
    const int panel = pc >> 4;              // 64 panels of 128 rows
    const int chunk = pc & 15;              // 16 chunks of 32 halves
    const float* src = isE ? E : X;
    _Float16* dst = isE ? Eh : Xh;
    const int t = threadIdx.x;
    const int row = t >> 1;                 // [0,128)
    const int kh  = (t & 1) * 16;
    const float* p = &src[(size_t)(panel * 128 + row) * Dn + chunk * 32 + kh];
    float4 v[4];
    v[0] = *(const float4*)(p + 0);
    v[1] = *(const float4*)(p + 4);
    v[2] = *(const float4*)(p + 8);
    v[3] = *(const float4*)(p + 12);
    const int slotbase = ((row >> 6) << 8) + (((row >> 4) & 3) << 6) + (row & 15);
    #pragma unroll
    for (int j = 0; j < 2; ++j) {
        half8 h;
        #pragma unroll
        for (int q = 0; q < 2; ++q) {
            const float4 w = v[j * 2 + q];
            h[q*4+0]=(_Float16)w.x; h[q*4+1]=(_Float16)w.y;
            h[q*4+2]=(_Float16)w.z; h[q*4+3]=(_Float16)w.w;
        }
        const int kq = (t & 1) * 2 + j;
        const size_t off = ((size_t)(panel * 16 + chunk) * 512
                            + slotbase + kq * 16) * 8;
        *(half8*)&dst[off] = h;
    }
    if (isE) {
        float s = 0.f;
        #pragma unroll
        for (int i = 0; i < 4; ++i)
            s += v[i].x*v[i].x + v[i].y*v[i].y + v[i].z*v[i].z + v[i].w*v[i].w;
        s += __shfl_xor(s, 1);              // pair (kh=0, kh=16) -> 32-col partial
        if ((t & 1) == 0) atomicAdd(&esq[panel * 128 + row], s);
    }
}

// ---------------- kernel: hi-only MFMA, 128x256, ALL-DIRECT (no staging) -----
// d~(b,k) = e_sq[k] - 2*(xh.eh). Wave tile 64x64 (acc 4x4), 8 waves (wm2 x
// wn4), __launch_bounds__(512,4) -> 128 unified regs -> 4 waves/SIMD, 2
// blocks/CU. LEDGER: occupancy +15% (r8), B-direct +9% (r15); depth (r10),
// phase discipline (r4), barrier halving (r16) all NULL; MfmaUtil pinned 36%
// = 33us MFMA-floor / 85us with NO saturated counter -> residual is the
// staging+barrier machinery itself (convoy formation). r17: A is ALSO a
// contiguous 64B/lane read in the packed layout -> load BOTH operands direct
// global->VGPR. Zero LDS staging, ZERO main-loop barriers; waves free-run,
// compiler software-pipelines the unrolled 16-chunk loop under the 128-reg
// cap. Duplication (4x A across wn, 2x B across wm) hits identical lines
// within a chunk window -> L1-served; unique traffic L2-resident (by-panel
// reuse + bx%8 XCD swizzle). A+B ~2GB chip-wide / ~60us ~ 33 TB/s L1+L2 -
// feasible. Only the epilogue __syncthreads survives (4KB merge buffer).
__global__ __launch_bounds__(512, 4) void argmin_hi(
    const _Float16* __restrict__ Xh, const _Float16* __restrict__ Eh,
    const float* __restrict__ esq, float* __restrict__ bestf)
{
    __shared__ __align__(16) float2 sm[512];   // 4KB cross-wn merge buffer

    const int tid  = threadIdx.x;
    const int bid  = blockIdx.x;
    const int bx   = bid & 31;           // 32 col-blocks of 256 (bx%8 -> XCD set)
    const int by   = bid >> 5;           // 64 row-blocks of 128
    const int lane = tid & 63, wave = tid >> 6;
    const int wm   = wave >> 2;          // 0..1: 64-row half
    const int wn   = wave & 3;           // 0..3: 64-col quarter
    const int colg = lane & 15, quad = lane >> 4;
    const int la8  = lane * 8;

    // per-wave operand bases in the packed layout (both contiguous 64B/lane)
    const _Float16* gA = Xh + (size_t)by * 65536 + wm * 2048 + la8;
    const _Float16* gB = Eh + (size_t)(2 * bx + (wn >> 1)) * 65536
                            + (wn & 1) * 2048 + la8;

    floatx4 acc[4][4];
    #pragma unroll
    for (int i = 0; i < 4; ++i)
        #pragma unroll
        for (int j = 0; j < 4; ++j) acc[i][j] = {0.f, 0.f, 0.f, 0.f};

    #pragma unroll
    for (int t = 0; t < 16; ++t) {
        half8 a[4], bb[4];
        #pragma unroll
        for (int mi = 0; mi < 4; ++mi)
            a[mi] = *(const half8*)(gA + t * 4096 + mi * 512);
        #pragma unroll
        for (int ni = 0; ni < 4; ++ni)
            bb[ni] = *(const half8*)(gB + t * 4096 + ni * 512);

        __builtin_amdgcn_s_setprio(1);
        #pragma unroll
        for (int mi = 0; mi < 4; ++mi)
            #pragma unroll
            for (int ni = 0; ni < 4; ++ni)
                acc[mi][ni] = __builtin_amdgcn_mfma_f32_16x16x32_f16(
                    a[mi], bb[ni], acc[mi][ni], 0, 0, 0);
        __builtin_amdgcn_s_setprio(0);
    }

    // ---- epilogue: per-(mi,r) top-2 over the wave's 64 cols, then cross-wn
    // merge in LDS -> top-2 per 256-col block (encoding identical to r3/r8).
    const int n0 = bx * 256 + wn * 64;
    float eqv[4];
    #pragma unroll
    for (int ni = 0; ni < 4; ++ni) eqv[ni] = esq[n0 + ni * 16 + colg];
    const unsigned ob_base = ((unsigned)colg << 4) | ((unsigned)wn << 2);

    #pragma unroll
    for (int mi = 0; mi < 4; ++mi)
        #pragma unroll
        for (int r = 0; r < 4; ++r) {
            float w1 = INFINITY, w2 = INFINITY;
            #pragma unroll
            for (int ni = 0; ni < 4; ++ni) {
                const float dv = eqv[ni] - 2.0f * acc[mi][ni][r];
                const float key = __uint_as_float(
                    (__float_as_uint(dv) & 0xFFFFFF00u) | (ob_base | (unsigned)ni));
                w2 = fminf(w2, fmaxf(w1, key));
                w1 = fminf(w1, key);
            }
            #pragma unroll
            for (int off = 1; off < 16; off <<= 1) {
                const float p1 = __shfl_xor(w1, off);
                const float p2 = __shfl_xor(w2, off);
                w2 = fminf(fmaxf(w1, p1), fminf(w2, p2));
                w1 = fminf(w1, p1);
            }
            if (colg == 0) {
                const int row128 = wm * 64 + mi * 16 + quad * 4 + r;
                float2 st; st.x = w1; st.y = w2;
                sm[row128 * 4 + wn] = st;
            }
        }
    __syncthreads();
    if (tid < 128) {
        float m1 = INFINITY, m2 = INFINITY;
        #pragma unroll
        for (int w = 0; w < 4; ++w) {
            const float2 p = sm[tid * 4 + w];
            m2 = fminf(fmaxf(m1, p.x), fminf(m2, p.y));
            m1 = fminf(m1, p.x);
        }
        float2 st; st.x = m1; st.y = m2;
        *(float2*)&bestf[(size_t)(by * 128 + tid) * 64 + bx * 2] = st;
    }
}

// ---------------- kernel: exact refine, ONE WAVE PER ROW ---------------------
// 64 lanes read the row's 64 stored keys (top-2 per 256-col block), wave-min
// -> threshold -> ballot survivors -> exact fp32 distance per survivor ->
// best index (u64 key: ties to lowest index) -> write index + residual.
// r12: winning k<bestk branch is wave-uniform -> carry winning row's e0/e1
// in registers, no final E[idx] re-read.
__global__ __launch_bounds__(256) void refine_kernel(
    const float* __restrict__ X, const float* __restrict__ E,
    const float* __restrict__ bestf, float* __restrict__ out)
{
    const int lane = threadIdx.x & 63, wave = threadIdx.x >> 6;
    const int b = blockIdx.x * 4 + wave;

    const float val = bestf[(size_t)b * 64 + lane];
    // decode this slot's candidate column: slot = cb*2 + j, cb = 256-col block
    const unsigned bits = __float_as_uint(val);
    const int cb = lane >> 1;
    const int colg = (bits >> 4) & 15, wn = (bits >> 2) & 3, ni = bits & 3;
    const int col = cb * 256 + wn * 64 + ni * 16 + colg;

    float mn = val;
    #pragma unroll
    for (int off = 1; off < 64; off <<= 1) mn = fminf(mn, __shfl_xor(mn, off));

    const float4* xr = (const float4*)(X + (size_t)b * Dn);
    const float4 x0 = xr[lane * 2], x1 = xr[lane * 2 + 1];

    u64 bestk = ~0ull;
    float4 be0, be1;                       // winning row's slice (wave-uniform upd)
    u64 mask = __ballot(val <= mn + WINDOW);
    while (mask) {
        const int s = __builtin_ctzll(mask);
        mask &= mask - 1;
        const int c = __shfl(col, s);
        const float4* er = (const float4*)(E + (size_t)c * Dn);
        const float4 e0 = er[lane * 2], e1 = er[lane * 2 + 1];
        float p = e0.x*(e0.x - 2.f*x0.x) + e0.y*(e0.y - 2.f*x0.y)
                + e0.z*(e0.z - 2.f*x0.z) + e0.w*(e0.w - 2.f*x0.w)
                + e1.x*(e1.x - 2.f*x1.x) + e1.y*(e1.y - 2.f*x1.y)
                + e1.z*(e1.z - 2.f*x1.z) + e1.w*(e1.w - 2.f*x1.w);
        #pragma unroll
        for (int off = 1; off < 64; off <<= 1) p += __shfl_xor(p, off);
        const u64 k = ((u64)fkey(p) << 32) | (u64)(unsigned int)c;
        if (k < bestk) { bestk = k; be0 = e0; be1 = e1; }
    }

    const int idx = (int)(unsigned int)(bestk & 0xFFFFFFFFull);
    if (lane == 0) out[b] = (float)idx;
    float4 r0, r1;
    r0.x = x0.x - be0.x; r0.y = x0.y - be0.y; r0.z = x0.z - be0.z; r0.w = x0.w - be0.w;
    r1.x = x1.x - be1.x; r1.y = x1.y - be1.y; r1.z = x1.z - be1.z; r1.w = x1.w - be1.w;
    float4* o = (float4*)(out + Bn + (size_t)b * Dn);
    o[lane * 2] = r0; o[lane * 2 + 1] = r1;
}

// ---------------- fallback (round-1 fp32 path, used only if ws too small) ----
#define KSPLIT 16
#define LDSW 132
__global__ __launch_bounds__(256, 2) void argmin_fp32(
    const float* __restrict__ X, const float* __restrict__ E,
    const float* __restrict__ esq, u64* __restrict__ best)
{
    __shared__ __align__(16) float Xs[16][LDSW];
    __shared__ __align__(16) float Es[16][LDSW];
    __shared__ u64 red[128][16];
    const int tid = threadIdx.x;
    const int tx = tid & 15, ty = tid >> 4;
    const int rowTile = blockIdx.x / KSPLIT;
    const int split   = blockIdx.x % KSPLIT;
    const int m0 = rowTile * 128;
    const int kbase = split * (Kn / KSPLIT);
    float bestv[8]; int besti[8];
    #pragma unroll
    for (int i = 0; i < 8; ++i) { bestv[i] = INFINITY; besti[i] = 0; }
    const int ldRow = tid >> 2, ldD = (tid & 3) * 4;
    for (int kt = 0; kt < (Kn / KSPLIT) / 128; ++kt) {
        const int k0 = kbase + kt * 128;
        float acc[8][8] = {};
        for (int dc = 0; dc < Dn / 16; ++dc) {
            const int d0 = dc * 16;
            float4 xa = *(const float4*)&X[(size_t)(m0 + ldRow)      * Dn + d0 + ldD];
            float4 xb = *(const float4*)&X[(size_t)(m0 + 64 + ldRow) * Dn + d0 + ldD];
            float4 ea = *(const float4*)&E[(size_t)(k0 + ldRow)      * Dn + d0 + ldD];
            float4 eb = *(const float4*)&E[(size_t)(k0 + 64 + ldRow) * Dn + d0 + ldD];
            __syncthreads();
            Xs[ldD+0][ldRow] = xa.x; Xs[ldD+1][ldRow] = xa.y;
            Xs[ldD+2][ldRow] = xa.z; Xs[ldD+3][ldRow] = xa.w;
            Xs[ldD+0][64+ldRow] = xb.x; Xs[ldD+1][64+ldRow] = xb.y;
            Xs[ldD+2][64+ldRow] = xb.z; Xs[ldD+3][64+ldRow] = xb.w;
            Es[ldD+0][ldRow] = ea.x; Es[ldD+1][ldRow] = ea.y;
            Es[ldD+2][ldRow] = ea.z; Es[ldD+3][ldRow] = ea.w;
            Es[ldD+0][64+ldRow] = eb.x; Es[ldD+1][64+ldRow] = eb.y;
            Es[ldD+2][64+ldRow] = eb.z; Es[ldD+3][64+ldRow] = eb.w;
            __syncthreads();
            #pragma unroll
            for (int d = 0; d < 16; ++d) {
                float a8[8], b8[8];
                *(float4*)&a8[0] = *(const float4*)&Xs[d][4*ty];
                *(float4*)&a8[4] = *(const float4*)&Xs[d][64 + 4*ty];
                *(float4*)&b8[0] = *(const float4*)&Es[d][4*tx];
                *(float4*)&b8[4] = *(const float4*)&Es[d][64 + 4*tx];
                #pragma unroll
                for (int i = 0; i < 8; ++i)
                    #pragma unroll
                    for (int j = 0; j < 8; ++j) acc[i][j] += a8[i] * b8[j];
            }
        }
        #pragma unroll
        for (int j = 0; j < 8; ++j) {
            const int c = k0 + ((j < 4) ? (4*tx + j) : (64 + 4*tx + (j - 4)));
            const float eq = esq[c];
            #pragma unroll
            for (int i = 0; i < 8; ++i) {
                float dval = eq - 2.0f * acc[i][j];
                if (dval < bestv[i]) { bestv[i] = dval; besti[i] = c; }
            }
        }
    }
    #pragma unroll
    for (int i = 0; i < 8; ++i) {
        int rloc = (i < 4) ? (4*ty + i) : (64 + 4*ty + (i - 4));
        red[rloc][tx] = ((u64)fkey(bestv[i]) << 32) | (u64)(unsigned int)besti[i];
    }
    __syncthreads();
    if (tid < 128) {
        u64 m = red[tid][0];
        #pragma unroll
        for (int t = 1; t < 16; ++t) { u64 v = red[tid][t]; if (v < m) m = v; }
        best[(size_t)(m0 + tid) * KSPLIT + split] = m;
    }
}

__global__ __launch_bounds__(256) void finalize_kernel(
    const float* __restrict__ X, const float* __restrict__ E,
    const u64* __restrict__ best, float* __restrict__ out, int nsplits)
{
    __shared__ int sidx[2];
    const int half = threadIdx.x >> 7;
    const int t    = threadIdx.x & 127;
    const int b    = blockIdx.x * 2 + half;
    if (t < 64) {
        u64 v = (t < nsplits) ? best[(size_t)b * nsplits + t] : ~0ull;
        #pragma unroll
        for (int off = 1; off < 64; off <<= 1) {
            u64 o = __shfl_xor(v, off);
            if (o < v) v = o;
        }
        if (t == 0) {
            int idx = (int)(unsigned int)(v & 0xFFFFFFFFull);
            sidx[half] = idx;
            out[b] = (float)idx;
        }
    }
    __syncthreads();
    const int idx = sidx[half];
    float4 x = ((const float4*)(X + (size_t)b * Dn))[t];
    float4 e = ((const float4*)(E + (size_t)idx * Dn))[t];
    float4 r; r.x = x.x - e.x; r.y = x.y - e.y; r.z = x.z - e.z; r.w = x.w - e.w;
    ((float4*)(out + Bn + (size_t)b * Dn))[t] = r;
}

extern "C" void kernel_launch(void* const* d_in, const int* in_sizes, int n_in,
                              void* d_out, int out_size, void* d_ws, size_t ws_size,
                              hipStream_t stream) {
    const float* X = (const float*)d_in[0];   // previous_residual [B, D]
    const float* E = (const float*)d_in[1];   // codebook_embeddings [K, D]
    float* out = (float*)d_out;               // [B] idx-as-float ++ [B*D] residual

    // fast-path ws: esq 32KB | Xh 8MB | Eh 8MB | bestf 2MB  (~18.3 MB)
    const size_t HB = (size_t)Bn * Dn * sizeof(_Float16);        // 8 MB
    const size_t BESTB = (size_t)Bn * 64 * sizeof(float);        // 2 MB
    const size_t NEED = 32768 + 2 * HB + BESTB;

    float* esq = (float*)d_ws;

    if (ws_size >= NEED) {
        _Float16* Xh = (_Float16*)((char*)d_ws + 32768);
        _Float16* Eh = (_Float16*)((char*)d_ws + 32768 + HB);
        float* bestf = (float*)((char*)d_ws + 32768 + 2 * HB);
        hipMemsetAsync((void*)esq, 0, Kn * sizeof(float), stream);
        convert_hi<<<2048, 256, 0, stream>>>(X, E, Xh, Eh, esq);
        argmin_hi<<<2048, 512, 0, stream>>>(Xh, Eh, esq, bestf);
        refine_kernel<<<Bn / 4, 256, 0, stream>>>(X, E, bestf, out);
    } else {
        u64* best = (u64*)((char*)d_ws + 32768);
        esq_kernel<<<Kn / 4, 256, 0, stream>>>(E, esq);
        argmin_fp32<<<(Bn / 128) * KSPLIT, 256, 0, stream>>>(X, E, esq, best);
        finalize_kernel<<<Bn / 2, 256, 0, stream>>>(X, E, best, out, KSPLIT);
    }
}